// Round 6
// baseline (930.805 us; speedup 1.0000x reference)
//
#include <hip/hip_runtime.h>

typedef __attribute__((ext_vector_type(8))) short short8;
typedef __attribute__((ext_vector_type(4))) float f32x4;
typedef __attribute__((ext_vector_type(4))) unsigned short u16x4;

__device__ __forceinline__ unsigned short f2bf(float f){
  unsigned int u = __builtin_bit_cast(unsigned int, f);
  u = (u + 0x7FFFu + ((u >> 16) & 1u)) >> 16;
  return (unsigned short)u;
}
__device__ __forceinline__ float bf2f(unsigned short h){
  unsigned int u = ((unsigned int)h) << 16;
  return __builtin_bit_cast(float, u);
}
__device__ __forceinline__ f32x4 mfma16(short8 a, short8 b, f32x4 c){
  return __builtin_amdgcn_mfma_f32_16x16x32_bf16(a, b, c, 0, 0, 0);
}
// async global->LDS, 16B/lane; lds base wave-uniform (HW: base + lane*16)
__device__ __forceinline__ void gload16(const void* g, void* l){
  __builtin_amdgcn_global_load_lds((const __attribute__((address_space(1))) void*)g,
                                   (__attribute__((address_space(3))) void*)l, 16, 0, 0);
}
// granule swizzle for linear [rows][32]-bf16 tiles (granule = 16B = 8 bf16)
__device__ __forceinline__ int swz_g(int r, int b){ return (r << 2) | (b ^ ((r >> 1) & 3)); }

// ---------------- f32 -> bf16 conversion (exactly 512*512 elems) ----------
__global__ __launch_bounds__(256) void cvt_f32_bf16(const float* __restrict__ src,
                                                    unsigned short* __restrict__ dst){
  int i = (blockIdx.x * 256 + threadIdx.x) * 4;
  float4 v = *(const float4*)(src + i);
  u16x4 o = { f2bf(v.x), f2bf(v.y), f2bf(v.z), f2bf(v.w) };
  *(u16x4*)(dst + i) = o;
}

// ---------------- LayerNorm over D=512, one wave per row, bf16 out --------
__global__ __launch_bounds__(256) void ln_rows(const float* __restrict__ x,
                                               const float* __restrict__ g,
                                               const float* __restrict__ b,
                                               unsigned short* __restrict__ y,
                                               int nrows){
  const int wid = threadIdx.x >> 6, lane = threadIdx.x & 63;
  const int row = blockIdx.x * 4 + wid;
  if (row >= nrows) return;
  const float* xr = x + (long)row * 512;
  float4 v0 = *(const float4*)(xr + lane * 4);
  float4 v1 = *(const float4*)(xr + 256 + lane * 4);
  float s  = v0.x + v0.y + v0.z + v0.w + v1.x + v1.y + v1.z + v1.w;
  float s2 = v0.x*v0.x + v0.y*v0.y + v0.z*v0.z + v0.w*v0.w
           + v1.x*v1.x + v1.y*v1.y + v1.z*v1.z + v1.w*v1.w;
  #pragma unroll
  for (int m = 1; m < 64; m <<= 1){ s += __shfl_xor(s, m); s2 += __shfl_xor(s2, m); }
  const float mu = s * (1.f/512.f);
  const float rstd = rsqrtf(s2 * (1.f/512.f) - mu*mu + 1e-5f);
  float4 g0 = *(const float4*)(g + lane*4), g1 = *(const float4*)(g + 256 + lane*4);
  float4 b0 = *(const float4*)(b + lane*4), b1 = *(const float4*)(b + 256 + lane*4);
  u16x4 o0 = { f2bf((v0.x-mu)*rstd*g0.x + b0.x), f2bf((v0.y-mu)*rstd*g0.y + b0.y),
               f2bf((v0.z-mu)*rstd*g0.z + b0.z), f2bf((v0.w-mu)*rstd*g0.w + b0.w) };
  u16x4 o1 = { f2bf((v1.x-mu)*rstd*g1.x + b1.x), f2bf((v1.y-mu)*rstd*g1.y + b1.y),
               f2bf((v1.z-mu)*rstd*g1.z + b1.z), f2bf((v1.w-mu)*rstd*g1.w + b1.w) };
  *(u16x4*)(y + (long)row * 512 + lane * 4) = o0;
  *(u16x4*)(y + (long)row * 512 + 256 + lane * 4) = o1;
}

// ---- prep: Wl'[n][c]=Wl[n][c]*g2[c] (bf16); u[n]=sum Wl'; v[n]=Wl.b2+bl;
//      bias_cat[n]=bo[n]; bias_cat[512+n]=c2[n]=sum Wl'[n][c]*bo[c] ---------
__global__ __launch_bounds__(256) void ln_weight_prep(
    const float* __restrict__ Wl, const float* __restrict__ g2,
    const float* __restrict__ b2, const float* __restrict__ bl,
    const float* __restrict__ bo,
    unsigned short* __restrict__ wlp, float* __restrict__ u,
    float* __restrict__ v, float* __restrict__ bias_cat){
  const int wid = threadIdx.x >> 6, lane = threadIdx.x & 63;
  const int n = blockIdx.x * 4 + wid;
  const float* row = Wl + (long)n * 512;
  float su = 0.f, sv = 0.f, sc = 0.f;
  #pragma unroll
  for (int h = 0; h < 2; ++h){
    const int c0 = h * 256 + lane * 4;
    float4 w  = *(const float4*)(row + c0);
    float4 gg = *(const float4*)(g2 + c0);
    float4 bb = *(const float4*)(b2 + c0);
    float4 oo = *(const float4*)(bo + c0);
    float4 wp = { w.x*gg.x, w.y*gg.y, w.z*gg.z, w.w*gg.w };
    su += wp.x + wp.y + wp.z + wp.w;
    sv += w.x*bb.x + w.y*bb.y + w.z*bb.z + w.w*bb.w;
    sc += wp.x*oo.x + wp.y*oo.y + wp.z*oo.z + wp.w*oo.w;
    u16x4 o = { f2bf(wp.x), f2bf(wp.y), f2bf(wp.z), f2bf(wp.w) };
    *(u16x4*)(wlp + (long)n * 512 + c0) = o;
  }
  #pragma unroll
  for (int m = 1; m < 64; m <<= 1){
    su += __shfl_xor(su, m); sv += __shfl_xor(sv, m); sc += __shfl_xor(sc, m);
  }
  if (lane == 0){
    u[n] = su;
    v[n] = sv + bl[n];
    bias_cat[n] = bo[n];
    bias_cat[512 + n] = sc;
  }
}

// ---- transpose 512x512: dst[k][c] = bf16(src[c][k]) ----------------------
__global__ __launch_bounds__(256) void transpose_bf(const float* __restrict__ src,
                                                    unsigned short* __restrict__ dst){
  __shared__ float tile[64][65];
  const int t = threadIdx.x;
  const int k0 = blockIdx.x * 64, c0 = blockIdx.y * 64;
  const int j = t & 63, i = t >> 6;
  #pragma unroll
  for (int rr = 0; rr < 16; ++rr)
    tile[i + rr*4][j] = src[(long)(c0 + i + rr*4) * 512 + k0 + j];
  __syncthreads();
  #pragma unroll
  for (int rr = 0; rr < 16; ++rr)
    dst[(long)(k0 + i + rr*4) * 512 + c0 + j] = f2bf(tile[j][i + rr*4]);
}

// ---------------- C = A(rows x 512) * B(512 x 512)^T + bias ---------------
__global__ __launch_bounds__(256) void gemm_bt(const unsigned short* __restrict__ A,
                                               const unsigned short* __restrict__ B,
                                               const float* __restrict__ bias,
                                               unsigned short* __restrict__ out,
                                               int transposed){
  __shared__ unsigned short At[128][40];
  __shared__ unsigned short Bt[128][40];
  const int t = threadIdx.x, lane = t & 63, wid = t >> 6;
  const int l15 = lane & 15, l4 = lane >> 4;
  const int wr = wid >> 1, wc = wid & 1;
  const int rowBase = blockIdx.y * 128;
  const int colBase = blockIdx.x * 128;
  f32x4 zero = {0.f, 0.f, 0.f, 0.f};
  f32x4 acc[4][4];
  #pragma unroll
  for (int i = 0; i < 4; ++i)
    #pragma unroll
    for (int j = 0; j < 4; ++j) acc[i][j] = zero;
  const int sr = t >> 1, sh = (t & 1) * 16;
  for (int ks = 0; ks < 16; ++ks){
    const int k0 = ks * 32;
    const unsigned short* sa = A + (long)(rowBase + sr) * 512 + k0 + sh;
    *(short8*)&At[sr][sh]     = *(const short8*)sa;
    *(short8*)&At[sr][sh + 8] = *(const short8*)(sa + 8);
    const unsigned short* sb = B + (long)(colBase + sr) * 512 + k0 + sh;
    *(short8*)&Bt[sr][sh]     = *(const short8*)sb;
    *(short8*)&Bt[sr][sh + 8] = *(const short8*)(sb + 8);
    __syncthreads();
    short8 af[4], bfv[4];
    #pragma unroll
    for (int i = 0; i < 4; ++i) af[i]  = *(const short8*)&At[wr*64 + i*16 + l15][l4*8];
    #pragma unroll
    for (int i = 0; i < 4; ++i) bfv[i] = *(const short8*)&Bt[wc*64 + i*16 + l15][l4*8];
    #pragma unroll
    for (int i = 0; i < 4; ++i)
      #pragma unroll
      for (int j = 0; j < 4; ++j)
        acc[i][j] = mfma16(af[i], bfv[j], acc[i][j]);
    __syncthreads();
  }
  #pragma unroll
  for (int i = 0; i < 4; ++i){
    const int r0 = rowBase + wr*64 + i*16 + l4*4;
    #pragma unroll
    for (int j = 0; j < 4; ++j){
      const int c = colBase + wc*64 + j*16 + l15;
      const float bb = bias ? bias[c] : 0.f;
      #pragma unroll
      for (int jr = 0; jr < 4; ++jr){
        const float v = acc[i][j][jr] + bb;
        const long rr = r0 + jr;
        if (!transposed){
          out[rr * 512 + c] = f2bf(v);
        } else {
          const long m = rr >> 7, s = rr & 127;
          out[(m * 512 + c) * 128 + s] = f2bf(v);
        }
      }
    }
  }
}

// ---------------- fused K,V projection: shares A staging ------------------
__global__ __launch_bounds__(256) void gemm_kv(const unsigned short* __restrict__ A,
                                               const unsigned short* __restrict__ Bk,
                                               const float* __restrict__ bkb,
                                               const unsigned short* __restrict__ Bv,
                                               const float* __restrict__ bvb,
                                               unsigned short* __restrict__ kout,
                                               unsigned short* __restrict__ vout){
  __shared__ unsigned short At[128][40];
  __shared__ unsigned short Kt[128][40];
  __shared__ unsigned short Vt[128][40];
  const int t = threadIdx.x, lane = t & 63, wid = t >> 6;
  const int l15 = lane & 15, l4 = lane >> 4;
  const int wr = wid >> 1, wc = wid & 1;
  const int rowBase = blockIdx.y * 128;
  const int colBase = blockIdx.x * 128;
  f32x4 zero = {0.f, 0.f, 0.f, 0.f};
  f32x4 acck[4][4], accv[4][4];
  #pragma unroll
  for (int i = 0; i < 4; ++i)
    #pragma unroll
    for (int j = 0; j < 4; ++j){ acck[i][j] = zero; accv[i][j] = zero; }
  const int sr = t >> 1, sh = (t & 1) * 16;
  for (int ks = 0; ks < 16; ++ks){
    const int k0 = ks * 32;
    const unsigned short* sa = A + (long)(rowBase + sr) * 512 + k0 + sh;
    *(short8*)&At[sr][sh]     = *(const short8*)sa;
    *(short8*)&At[sr][sh + 8] = *(const short8*)(sa + 8);
    const unsigned short* sk = Bk + (long)(colBase + sr) * 512 + k0 + sh;
    *(short8*)&Kt[sr][sh]     = *(const short8*)sk;
    *(short8*)&Kt[sr][sh + 8] = *(const short8*)(sk + 8);
    const unsigned short* sv = Bv + (long)(colBase + sr) * 512 + k0 + sh;
    *(short8*)&Vt[sr][sh]     = *(const short8*)sv;
    *(short8*)&Vt[sr][sh + 8] = *(const short8*)(sv + 8);
    __syncthreads();
    short8 af[4], kf[4], vf[4];
    #pragma unroll
    for (int i = 0; i < 4; ++i) af[i] = *(const short8*)&At[wr*64 + i*16 + l15][l4*8];
    #pragma unroll
    for (int i = 0; i < 4; ++i) kf[i] = *(const short8*)&Kt[wc*64 + i*16 + l15][l4*8];
    #pragma unroll
    for (int i = 0; i < 4; ++i) vf[i] = *(const short8*)&Vt[wc*64 + i*16 + l15][l4*8];
    #pragma unroll
    for (int i = 0; i < 4; ++i)
      #pragma unroll
      for (int j = 0; j < 4; ++j){
        acck[i][j] = mfma16(af[i], kf[j], acck[i][j]);
        accv[i][j] = mfma16(af[i], vf[j], accv[i][j]);
      }
    __syncthreads();
  }
  const long m = blockIdx.y; // 128 rows per block == one music index
  #pragma unroll
  for (int i = 0; i < 4; ++i){
    const int r0 = rowBase + wr*64 + i*16 + l4*4;
    #pragma unroll
    for (int j = 0; j < 4; ++j){
      const int c = colBase + wc*64 + j*16 + l15;
      const float kb = bkb[c], vb = bvb[c];
      #pragma unroll
      for (int jr = 0; jr < 4; ++jr){
        const long rr = r0 + jr;
        kout[rr * 512 + c] = f2bf(acck[i][j][jr] + kb);
        const long s = rr & 127;
        vout[(m * 512 + c) * 128 + s] = f2bf(accv[i][j][jr] + vb);
      }
    }
  }
}

// ---------------- attention: per (m, 32-row q block) ----------------------
__global__ __launch_bounds__(256) void attn_kernel(const unsigned short* __restrict__ q,
                                                   const unsigned short* __restrict__ k,
                                                   const unsigned short* __restrict__ vT,
                                                   const int* __restrict__ mask,
                                                   unsigned short* __restrict__ attn){
  __shared__ __align__(16) char smem[58880];
  unsigned short (*q_lds)[520] = (unsigned short (*)[520])smem;
  unsigned short (*k_lds)[40]  = (unsigned short (*)[40])(smem + 33280);
  float (*lg)[132]             = (float (*)[132])(smem + 33280);
  unsigned short (*w_lds)[136] = (unsigned short (*)[136])(smem + 50176);
  unsigned short (*v_lds)[136] = (unsigned short (*)[136])smem;
  const int m = blockIdx.x >> 3, nb = blockIdx.x & 7;
  const int t = threadIdx.x, lane = t & 63, wid = t >> 6;
  const int l15 = lane & 15, l4 = lane >> 4;
  {
    const int r = t >> 3, c0 = (t & 7) * 64;
    const unsigned short* src = q + (long)(nb*32 + r) * 512 + c0;
    #pragma unroll
    for (int i = 0; i < 64; i += 8)
      *(short8*)&q_lds[r][c0 + i] = *(const short8*)(src + i);
  }
  f32x4 zero = {0.f,0.f,0.f,0.f};
  f32x4 acc[2][2];
  acc[0][0]=zero; acc[0][1]=zero; acc[1][0]=zero; acc[1][1]=zero;
  const int kr = t >> 1, kh = (t & 1) * 16;
  const unsigned short* kbase = k + (long)m * 128 * 512;
  for (int ks = 0; ks < 16; ++ks){
    const int k0 = ks * 32;
    const unsigned short* src = kbase + (long)kr * 512 + k0 + kh;
    *(short8*)&k_lds[kr][kh]     = *(const short8*)src;
    *(short8*)&k_lds[kr][kh + 8] = *(const short8*)(src + 8);
    __syncthreads();
    short8 af[2], bfv[2];
    #pragma unroll
    for (int i = 0; i < 2; ++i) af[i]  = *(const short8*)&q_lds[i*16 + l15][k0 + l4*8];
    #pragma unroll
    for (int i = 0; i < 2; ++i) bfv[i] = *(const short8*)&k_lds[wid*32 + i*16 + l15][l4*8];
    #pragma unroll
    for (int i = 0; i < 2; ++i)
      #pragma unroll
      for (int j = 0; j < 2; ++j)
        acc[i][j] = mfma16(af[i], bfv[j], acc[i][j]);
    __syncthreads();
  }
  const float scale = 0.04419417382415922f; // 1/sqrt(512)
  #pragma unroll
  for (int i = 0; i < 2; ++i)
    #pragma unroll
    for (int j = 0; j < 2; ++j)
      #pragma unroll
      for (int jr = 0; jr < 4; ++jr)
        lg[i*16 + l4*4 + jr][wid*32 + j*16 + l15] = acc[i][j][jr] * scale;
  __syncthreads();
  {
    const int row = t >> 3, u = t & 7;
    const int* mrow = mask + m * 128;
    float vals[16];
    float mx = -3.0e38f;
    #pragma unroll
    for (int i = 0; i < 16; ++i){
      const int s = u*16 + i;
      const float vv = (mrow[s] == 0) ? -3.0e38f : lg[row][s];
      vals[i] = vv;
      mx = fmaxf(mx, vv);
    }
    mx = fmaxf(mx, __shfl_xor(mx, 1));
    mx = fmaxf(mx, __shfl_xor(mx, 2));
    mx = fmaxf(mx, __shfl_xor(mx, 4));
    float sum = 0.f;
    #pragma unroll
    for (int i = 0; i < 16; ++i){
      const float e = __expf(vals[i] - mx);
      vals[i] = e;
      sum += e;
    }
    sum += __shfl_xor(sum, 1);
    sum += __shfl_xor(sum, 2);
    sum += __shfl_xor(sum, 4);
    const float inv = (sum > 0.f) ? (1.f / sum) : 0.f;
    #pragma unroll
    for (int i = 0; i < 16; i += 4){
      u16x4 o = { f2bf(vals[i]*inv), f2bf(vals[i+1]*inv),
                  f2bf(vals[i+2]*inv), f2bf(vals[i+3]*inv) };
      *(u16x4*)&w_lds[row][u*16 + i] = o;
    }
  }
  const long rowb = (long)m * 256 + nb * 32;
  const unsigned short* vbase = vT + (long)m * 512 * 128;
  for (int db = 0; db < 4; ++db){
    __syncthreads();
    {
      const int r = t >> 1, h = (t & 1) * 64;
      const unsigned short* src = vbase + (long)(db*128 + r) * 128 + h;
      #pragma unroll
      for (int i = 0; i < 64; i += 8)
        *(short8*)&v_lds[r][h + i] = *(const short8*)(src + i);
    }
    __syncthreads();
    f32x4 pacc[2][2];
    pacc[0][0]=zero; pacc[0][1]=zero; pacc[1][0]=zero; pacc[1][1]=zero;
    #pragma unroll
    for (int ks2 = 0; ks2 < 4; ++ks2){
      short8 wf[2], vf[2];
      #pragma unroll
      for (int i = 0; i < 2; ++i) wf[i] = *(const short8*)&w_lds[i*16 + l15][ks2*32 + l4*8];
      #pragma unroll
      for (int i = 0; i < 2; ++i) vf[i] = *(const short8*)&v_lds[wid*32 + i*16 + l15][ks2*32 + l4*8];
      #pragma unroll
      for (int i = 0; i < 2; ++i)
        #pragma unroll
        for (int j = 0; j < 2; ++j)
          pacc[i][j] = mfma16(wf[i], vf[j], pacc[i][j]);
    }
    #pragma unroll
    for (int i = 0; i < 2; ++i)
      #pragma unroll
      for (int j = 0; j < 2; ++j)
        #pragma unroll
        for (int jr = 0; jr < 4; ++jr)
          attn[(rowb + i*16 + l4*4 + jr) * 512 + db*128 + wid*32 + j*16 + l15] =
              f2bf(pacc[i][j][jr]);
  }
}

// ---- fused single-GEMM epilogue kernel (no K-loop barriers) --------------
// A (64x512) staged to LDS ONCE (granule-XOR swizzled source, linear dest);
// B (Bcat, 1MB, L2-resident) read directly to registers per fragment.
// C[64][1024] -> o|p split; LN2; lin=rstd*(p-mu*u)+v; y=oln+lin; LN3 -> out.
__global__ __launch_bounds__(512, 2) void fused_big(
    const unsigned short* __restrict__ attn,
    const unsigned short* __restrict__ Bcat, const float* __restrict__ bias_cat,
    const float* __restrict__ u, const float* __restrict__ v,
    const float* __restrict__ g2, const float* __restrict__ b2,
    const float* __restrict__ g3, const float* __restrict__ b3,
    float* __restrict__ out){
  extern __shared__ char smem[];
  unsigned short* A_lds = (unsigned short*)smem;                 // 65536 B (swz granules)
  unsigned short (*linb)[516] = (unsigned short (*)[516])smem;   // overlay post-K, 66048 B
  float (*rs1)[4] = (float (*)[4])(smem + 66048);                // 1024 B
  float (*rs2)[4] = (float (*)[4])(smem + 67072);                // 1024 B -> 68096 total
  const int t = threadIdx.x, lane = t & 63, wid = t >> 6;
  const int l15 = lane & 15, l4 = lane >> 4;
  const long rows0 = (long)blockIdx.x * 64;

  // one-time A stage: 64 rows x 64 granules, LDS slot p=(row,g'), src g = g'^(row&7)
  #pragma unroll
  for (int it = 0; it < 8; ++it){
    const int p = it*512 + t;
    const int row = p >> 6, gp = p & 63;
    const int gsrc = gp ^ (row & 7);
    gload16(attn + (rows0 + row)*512 + gsrc*8, A_lds + (long)p*8);
  }

  // per-lane B row bases for this wave's 128 cols (8 frags x 16 rows)
  const unsigned short* bptr[8];
  #pragma unroll
  for (int j = 0; j < 8; ++j)
    bptr[j] = Bcat + (long)(wid*128 + j*16 + l15) * 512 + l4*8;

  f32x4 zero = {0.f,0.f,0.f,0.f};
  f32x4 acc[4][8];
  #pragma unroll
  for (int i = 0; i < 4; ++i)
    #pragma unroll
    for (int j = 0; j < 8; ++j) acc[i][j] = zero;

  __syncthreads();                 // A_lds ready (compiler drains vmcnt)

  #pragma unroll
  for (int ks = 0; ks < 16; ++ks){
    short8 af[4], bfv[8];
    #pragma unroll
    for (int j = 0; j < 8; ++j) bfv[j] = *(const short8*)(bptr[j] + ks*32);
    #pragma unroll
    for (int i = 0; i < 4; ++i){
      const int row = i*16 + l15;
      const int gp = (ks*4 + l4) ^ (l15 & 7);
      af[i] = *(const short8*)(A_lds + (row*64 + gp)*8);
    }
    #pragma unroll
    for (int i = 0; i < 4; ++i)
      #pragma unroll
      for (int j = 0; j < 8; ++j)
        acc[i][j] = mfma16(af[i], bfv[j], acc[i][j]);
  }

  const int side = wid >> 2;         // 0: o-cols (0..511), 1: p-cols (512..1023)
  const int wq = wid & 3;            // 128-col strip within side
  // bias add; o-side LN2 partial stats
  float ps1[4][4], ps2[4][4];
  #pragma unroll
  for (int mi = 0; mi < 4; ++mi)
    #pragma unroll
    for (int jr = 0; jr < 4; ++jr){ ps1[mi][jr] = 0.f; ps2[mi][jr] = 0.f; }
  #pragma unroll
  for (int mi = 0; mi < 4; ++mi)
    #pragma unroll
    for (int ni = 0; ni < 8; ++ni){
      const int col = wid*128 + ni*16 + l15;       // 0..1023
      const float bb = bias_cat[col];
      #pragma unroll
      for (int jr = 0; jr < 4; ++jr){
        const float val = acc[mi][ni][jr] + bb;
        acc[mi][ni][jr] = val;
        if (side == 0){ ps1[mi][jr] += val; ps2[mi][jr] += val * val; }
      }
    }
  if (side == 0){
    #pragma unroll
    for (int mk = 1; mk < 16; mk <<= 1)
      #pragma unroll
      for (int mi = 0; mi < 4; ++mi)
        #pragma unroll
        for (int jr = 0; jr < 4; ++jr){
          ps1[mi][jr] += __shfl_xor(ps1[mi][jr], mk);
          ps2[mi][jr] += __shfl_xor(ps2[mi][jr], mk);
        }
  }
  __syncthreads();                   // all waves past K-loop (A_lds dead)
  if (side == 0 && l15 == 0){
    #pragma unroll
    for (int mi = 0; mi < 4; ++mi)
      #pragma unroll
      for (int jr = 0; jr < 4; ++jr){
        const int r = mi*16 + l4*4 + jr;
        rs1[r][wq] = ps1[mi][jr];
        rs2[r][wq] = ps2[mi][jr];
      }
  }
  __syncthreads();
  float mu2[4][4], rstd2[4][4];
  #pragma unroll
  for (int mi = 0; mi < 4; ++mi)
    #pragma unroll
    for (int jr = 0; jr < 4; ++jr){
      const int r = mi*16 + l4*4 + jr;
      const float s  = rs1[r][0] + rs1[r][1] + rs1[r][2] + rs1[r][3];
      const float sq = rs2[r][0] + rs2[r][1] + rs2[r][2] + rs2[r][3];
      const float m_ = s * (1.f/512.f);
      mu2[mi][jr] = m_;
      rstd2[mi][jr] = rsqrtf(sq * (1.f/512.f) - m_*m_ + 1e-5f);
    }
  __syncthreads();                   // rs reads done; linb region writable
  if (side == 1){
    #pragma unroll
    for (int mi = 0; mi < 4; ++mi)
      #pragma unroll
      for (int ni = 0; ni < 8; ++ni){
        const int n = wq*128 + ni*16 + l15;        // 0..511
        const float un = u[n], vn = v[n];
        #pragma unroll
        for (int jr = 0; jr < 4; ++jr){
          const int r = mi*16 + l4*4 + jr;
          const float lin = rstd2[mi][jr] * (acc[mi][ni][jr] - mu2[mi][jr] * un) + vn;
          linb[r][n] = f2bf(lin);
        }
      }
  }
  __syncthreads();
  if (side == 0){
    #pragma unroll
    for (int mi = 0; mi < 4; ++mi)
      #pragma unroll
      for (int jr = 0; jr < 4; ++jr){ ps1[mi][jr] = 0.f; ps2[mi][jr] = 0.f; }
    #pragma unroll
    for (int mi = 0; mi < 4; ++mi)
      #pragma unroll
      for (int ni = 0; ni < 8; ++ni){
        const int n = wq*128 + ni*16 + l15;
        const float gg = g2[n], bb = b2[n];
        #pragma unroll
        for (int jr = 0; jr < 4; ++jr){
          const int r = mi*16 + l4*4 + jr;
          const float oln = (acc[mi][ni][jr] - mu2[mi][jr]) * rstd2[mi][jr] * gg + bb;
          const float y = oln + bf2f(linb[r][n]);
          acc[mi][ni][jr] = y;
          ps1[mi][jr] += y;
          ps2[mi][jr] += y * y;
        }
      }
    #pragma unroll
    for (int mk = 1; mk < 16; mk <<= 1)
      #pragma unroll
      for (int mi = 0; mi < 4; ++mi)
        #pragma unroll
        for (int jr = 0; jr < 4; ++jr){
          ps1[mi][jr] += __shfl_xor(ps1[mi][jr], mk);
          ps2[mi][jr] += __shfl_xor(ps2[mi][jr], mk);
        }
  }
  __syncthreads();                   // linb reads done; rs reusable
  if (side == 0 && l15 == 0){
    #pragma unroll
    for (int mi = 0; mi < 4; ++mi)
      #pragma unroll
      for (int jr = 0; jr < 4; ++jr){
        const int r = mi*16 + l4*4 + jr;
        rs1[r][wq] = ps1[mi][jr];
        rs2[r][wq] = ps2[mi][jr];
      }
  }
  __syncthreads();
  if (side == 0){
    #pragma unroll
    for (int mi = 0; mi < 4; ++mi)
      #pragma unroll
      for (int jr = 0; jr < 4; ++jr){
        const int r = mi*16 + l4*4 + jr;
        const float s  = rs1[r][0] + rs1[r][1] + rs1[r][2] + rs1[r][3];
        const float sq = rs2[r][0] + rs2[r][1] + rs2[r][2] + rs2[r][3];
        const float m_ = s * (1.f/512.f);
        mu2[mi][jr] = m_;
        rstd2[mi][jr] = rsqrtf(sq * (1.f/512.f) - m_*m_ + 1e-5f);
      }
    #pragma unroll
    for (int mi = 0; mi < 4; ++mi)
      #pragma unroll
      for (int ni = 0; ni < 8; ++ni){
        const int n = wq*128 + ni*16 + l15;
        const float gg = g3[n], bb = b3[n];
        #pragma unroll
        for (int jr = 0; jr < 4; ++jr){
          const int r = mi*16 + l4*4 + jr;
          out[(rows0 + r) * 512 + n] =
              (acc[mi][ni][jr] - mu2[mi][jr]) * rstd2[mi][jr] * gg + bb;
        }
      }
  }
}

extern "C" void kernel_launch(void* const* d_in, const int* in_sizes, int n_in,
                              void* d_out, int out_size, void* d_ws, size_t ws_size,
                              hipStream_t stream){
  const float* video = (const float*)d_in[0];
  const float* music = (const float*)d_in[1];
  const int*   mask  = (const int*)d_in[2];
  const float* ln1g  = (const float*)d_in[3];
  const float* ln1b  = (const float*)d_in[4];
  const float* Wq = (const float*)d_in[5];  const float* bq = (const float*)d_in[6];
  const float* Wk = (const float*)d_in[7];  const float* bk = (const float*)d_in[8];
  const float* Wv = (const float*)d_in[9];  const float* bv = (const float*)d_in[10];
  const float* Wo = (const float*)d_in[11]; const float* bo = (const float*)d_in[12];
  const float* Wl = (const float*)d_in[13]; const float* bl = (const float*)d_in[14];
  const float* g2 = (const float*)d_in[15]; const float* b2 = (const float*)d_in[16];
  const float* g3 = (const float*)d_in[17]; const float* b3 = (const float*)d_in[18];

  // d_out doubles as scratch for stage-1/2 intermediates (dead before final write)
  char* ob = (char*)d_out;
  unsigned short* mln   = (unsigned short*)ob;                  // [65536][512] bf16
  unsigned short* kbuf  = (unsigned short*)(ob + 67108864);     // [65536][512] bf16
  unsigned short* vTbuf = (unsigned short*)(ob + 134217728);    // [512][512][128] bf16
  float* outp = (float*)d_out;

  char* wsb = (char*)d_ws;
  unsigned short* attnb = (unsigned short*)wsb;                 // [131072][512] bf16
  unsigned short* Wq_bf = (unsigned short*)(wsb + 134217728);
  unsigned short* Wk_bf = Wq_bf + 262144;
  unsigned short* Wv_bf = Wk_bf + 262144;
  unsigned short* q_ws  = Wv_bf + 262144;                       // [256][512] bf16
  unsigned short* vln   = q_ws + 131072;                        // [256][512] bf16
  unsigned short* Bcat  = vln + 131072;                         // [1024][512] bf16
  unsigned short* wlp   = Bcat + 524288;                        // [512][512] bf16
  unsigned short* WoT   = wlp + 262144;                         // [512][512] bf16
  float* bias_cat = (float*)(WoT + 262144);                     // [1024]
  float* u_vec    = bias_cat + 1024;                            // [512]
  float* v_vec    = u_vec + 512;                                // [512]

  cvt_f32_bf16<<<256, 256, 0, stream>>>(Wq, Wq_bf);
  cvt_f32_bf16<<<256, 256, 0, stream>>>(Wk, Wk_bf);
  cvt_f32_bf16<<<256, 256, 0, stream>>>(Wv, Wv_bf);
  cvt_f32_bf16<<<256, 256, 0, stream>>>(Wo, Bcat);              // Bcat rows 0..511 = Wo
  ln_weight_prep<<<128, 256, 0, stream>>>(Wl, g2, b2, bl, bo, wlp, u_vec, v_vec, bias_cat);
  transpose_bf<<<dim3(8, 8), 256, 0, stream>>>(Wo, WoT);
  gemm_bt<<<dim3(4, 4), 256, 0, stream>>>(wlp, WoT, nullptr, Bcat + 262144, 0); // W2

  ln_rows<<<16384, 256, 0, stream>>>(music, ln1g, ln1b, mln, 65536);
  ln_rows<<<64,    256, 0, stream>>>(video, ln1g, ln1b, vln, 256);

  gemm_bt<<<dim3(4, 2),   256, 0, stream>>>(vln, Wq_bf, bq, q_ws, 0);
  gemm_kv<<<dim3(4, 512), 256, 0, stream>>>(mln, Wk_bf, bk, Wv_bf, bv, kbuf, vTbuf);

  attn_kernel<<<4096, 256, 0, stream>>>(q_ws, kbuf, vTbuf, mask, attnb);

  (void)hipFuncSetAttribute(reinterpret_cast<const void*>(fused_big),
                            hipFuncAttributeMaxDynamicSharedMemorySize, 68096);
  fused_big<<<2048, 512, 68096, stream>>>(attnb, Bcat, bias_cat, u_vec, v_vec,
                                          g2, b2, g3, b3, outp);
}

// Round 7
// 888.912 us; speedup vs baseline: 1.0471x; 1.0471x over previous
//
#include <hip/hip_runtime.h>

typedef __attribute__((ext_vector_type(8))) short short8;
typedef __attribute__((ext_vector_type(4))) float f32x4;
typedef __attribute__((ext_vector_type(4))) unsigned short u16x4;

__device__ __forceinline__ unsigned short f2bf(float f){
  unsigned int u = __builtin_bit_cast(unsigned int, f);
  u = (u + 0x7FFFu + ((u >> 16) & 1u)) >> 16;
  return (unsigned short)u;
}
__device__ __forceinline__ float bf2f(unsigned short h){
  unsigned int u = ((unsigned int)h) << 16;
  return __builtin_bit_cast(float, u);
}
__device__ __forceinline__ f32x4 mfma16(short8 a, short8 b, f32x4 c){
  return __builtin_amdgcn_mfma_f32_16x16x32_bf16(a, b, c, 0, 0, 0);
}
// async global->LDS, 16B/lane; lds base wave-uniform (HW: base + lane*16)
__device__ __forceinline__ void gload16(const void* g, void* l){
  __builtin_amdgcn_global_load_lds((const __attribute__((address_space(1))) void*)g,
                                   (__attribute__((address_space(3))) void*)l, 16, 0, 0);
}

// ---------------- f32 -> bf16 conversion (exactly 512*512 elems) ----------
__global__ __launch_bounds__(256) void cvt_f32_bf16(const float* __restrict__ src,
                                                    unsigned short* __restrict__ dst){
  int i = (blockIdx.x * 256 + threadIdx.x) * 4;
  float4 v = *(const float4*)(src + i);
  u16x4 o = { f2bf(v.x), f2bf(v.y), f2bf(v.z), f2bf(v.w) };
  *(u16x4*)(dst + i) = o;
}

// ---------------- LayerNorm over D=512, one wave per row, bf16 out --------
__global__ __launch_bounds__(256) void ln_rows(const float* __restrict__ x,
                                               const float* __restrict__ g,
                                               const float* __restrict__ b,
                                               unsigned short* __restrict__ y,
                                               int nrows){
  const int wid = threadIdx.x >> 6, lane = threadIdx.x & 63;
  const int row = blockIdx.x * 4 + wid;
  if (row >= nrows) return;
  const float* xr = x + (long)row * 512;
  float4 v0 = *(const float4*)(xr + lane * 4);
  float4 v1 = *(const float4*)(xr + 256 + lane * 4);
  float s  = v0.x + v0.y + v0.z + v0.w + v1.x + v1.y + v1.z + v1.w;
  float s2 = v0.x*v0.x + v0.y*v0.y + v0.z*v0.z + v0.w*v0.w
           + v1.x*v1.x + v1.y*v1.y + v1.z*v1.z + v1.w*v1.w;
  #pragma unroll
  for (int m = 1; m < 64; m <<= 1){ s += __shfl_xor(s, m); s2 += __shfl_xor(s2, m); }
  const float mu = s * (1.f/512.f);
  const float rstd = rsqrtf(s2 * (1.f/512.f) - mu*mu + 1e-5f);
  float4 g0 = *(const float4*)(g + lane*4), g1 = *(const float4*)(g + 256 + lane*4);
  float4 b0 = *(const float4*)(b + lane*4), b1 = *(const float4*)(b + 256 + lane*4);
  u16x4 o0 = { f2bf((v0.x-mu)*rstd*g0.x + b0.x), f2bf((v0.y-mu)*rstd*g0.y + b0.y),
               f2bf((v0.z-mu)*rstd*g0.z + b0.z), f2bf((v0.w-mu)*rstd*g0.w + b0.w) };
  u16x4 o1 = { f2bf((v1.x-mu)*rstd*g1.x + b1.x), f2bf((v1.y-mu)*rstd*g1.y + b1.y),
               f2bf((v1.z-mu)*rstd*g1.z + b1.z), f2bf((v1.w-mu)*rstd*g1.w + b1.w) };
  *(u16x4*)(y + (long)row * 512 + lane * 4) = o0;
  *(u16x4*)(y + (long)row * 512 + 256 + lane * 4) = o1;
}

// ---- prep: Wl'[n][c]=Wl[n][c]*g2[c] (bf16); u[n]=sum Wl'; v[n]=Wl.b2+bl;
//      bias_cat[n]=bo[n]; bias_cat[512+n]=c2[n]=sum Wl'[n][c]*bo[c] ---------
__global__ __launch_bounds__(256) void ln_weight_prep(
    const float* __restrict__ Wl, const float* __restrict__ g2,
    const float* __restrict__ b2, const float* __restrict__ bl,
    const float* __restrict__ bo,
    unsigned short* __restrict__ wlp, float* __restrict__ u,
    float* __restrict__ v, float* __restrict__ bias_cat){
  const int wid = threadIdx.x >> 6, lane = threadIdx.x & 63;
  const int n = blockIdx.x * 4 + wid;
  const float* row = Wl + (long)n * 512;
  float su = 0.f, sv = 0.f, sc = 0.f;
  #pragma unroll
  for (int h = 0; h < 2; ++h){
    const int c0 = h * 256 + lane * 4;
    float4 w  = *(const float4*)(row + c0);
    float4 gg = *(const float4*)(g2 + c0);
    float4 bb = *(const float4*)(b2 + c0);
    float4 oo = *(const float4*)(bo + c0);
    float4 wp = { w.x*gg.x, w.y*gg.y, w.z*gg.z, w.w*gg.w };
    su += wp.x + wp.y + wp.z + wp.w;
    sv += w.x*bb.x + w.y*bb.y + w.z*bb.z + w.w*bb.w;
    sc += wp.x*oo.x + wp.y*oo.y + wp.z*oo.z + wp.w*oo.w;
    u16x4 o = { f2bf(wp.x), f2bf(wp.y), f2bf(wp.z), f2bf(wp.w) };
    *(u16x4*)(wlp + (long)n * 512 + c0) = o;
  }
  #pragma unroll
  for (int m = 1; m < 64; m <<= 1){
    su += __shfl_xor(su, m); sv += __shfl_xor(sv, m); sc += __shfl_xor(sc, m);
  }
  if (lane == 0){
    u[n] = su;
    v[n] = sv + bl[n];
    bias_cat[n] = bo[n];
    bias_cat[512 + n] = sc;
  }
}

// ---- transpose 512x512: dst[k][c] = bf16(src[c][k]) ----------------------
__global__ __launch_bounds__(256) void transpose_bf(const float* __restrict__ src,
                                                    unsigned short* __restrict__ dst){
  __shared__ float tile[64][65];
  const int t = threadIdx.x;
  const int k0 = blockIdx.x * 64, c0 = blockIdx.y * 64;
  const int j = t & 63, i = t >> 6;
  #pragma unroll
  for (int rr = 0; rr < 16; ++rr)
    tile[i + rr*4][j] = src[(long)(c0 + i + rr*4) * 512 + k0 + j];
  __syncthreads();
  #pragma unroll
  for (int rr = 0; rr < 16; ++rr)
    dst[(long)(k0 + i + rr*4) * 512 + c0 + j] = f2bf(tile[j][i + rr*4]);
}

// ---------------- C = A(rows x 512) * B(512 x 512)^T + bias ---------------
__global__ __launch_bounds__(256) void gemm_bt(const unsigned short* __restrict__ A,
                                               const unsigned short* __restrict__ B,
                                               const float* __restrict__ bias,
                                               unsigned short* __restrict__ out,
                                               int transposed){
  __shared__ unsigned short At[128][40];
  __shared__ unsigned short Bt[128][40];
  const int t = threadIdx.x, lane = t & 63, wid = t >> 6;
  const int l15 = lane & 15, l4 = lane >> 4;
  const int wr = wid >> 1, wc = wid & 1;
  const int rowBase = blockIdx.y * 128;
  const int colBase = blockIdx.x * 128;
  f32x4 zero = {0.f, 0.f, 0.f, 0.f};
  f32x4 acc[4][4];
  #pragma unroll
  for (int i = 0; i < 4; ++i)
    #pragma unroll
    for (int j = 0; j < 4; ++j) acc[i][j] = zero;
  const int sr = t >> 1, sh = (t & 1) * 16;
  for (int ks = 0; ks < 16; ++ks){
    const int k0 = ks * 32;
    const unsigned short* sa = A + (long)(rowBase + sr) * 512 + k0 + sh;
    *(short8*)&At[sr][sh]     = *(const short8*)sa;
    *(short8*)&At[sr][sh + 8] = *(const short8*)(sa + 8);
    const unsigned short* sb = B + (long)(colBase + sr) * 512 + k0 + sh;
    *(short8*)&Bt[sr][sh]     = *(const short8*)sb;
    *(short8*)&Bt[sr][sh + 8] = *(const short8*)(sb + 8);
    __syncthreads();
    short8 af[4], bfv[4];
    #pragma unroll
    for (int i = 0; i < 4; ++i) af[i]  = *(const short8*)&At[wr*64 + i*16 + l15][l4*8];
    #pragma unroll
    for (int i = 0; i < 4; ++i) bfv[i] = *(const short8*)&Bt[wc*64 + i*16 + l15][l4*8];
    #pragma unroll
    for (int i = 0; i < 4; ++i)
      #pragma unroll
      for (int j = 0; j < 4; ++j)
        acc[i][j] = mfma16(af[i], bfv[j], acc[i][j]);
    __syncthreads();
  }
  #pragma unroll
  for (int i = 0; i < 4; ++i){
    const int r0 = rowBase + wr*64 + i*16 + l4*4;
    #pragma unroll
    for (int j = 0; j < 4; ++j){
      const int c = colBase + wc*64 + j*16 + l15;
      const float bb = bias ? bias[c] : 0.f;
      #pragma unroll
      for (int jr = 0; jr < 4; ++jr){
        const float v = acc[i][j][jr] + bb;
        const long rr = r0 + jr;
        if (!transposed){
          out[rr * 512 + c] = f2bf(v);
        } else {
          const long m = rr >> 7, s = rr & 127;
          out[(m * 512 + c) * 128 + s] = f2bf(v);
        }
      }
    }
  }
}

// ---------------- fused K,V projection: shares A staging ------------------
__global__ __launch_bounds__(256) void gemm_kv(const unsigned short* __restrict__ A,
                                               const unsigned short* __restrict__ Bk,
                                               const float* __restrict__ bkb,
                                               const unsigned short* __restrict__ Bv,
                                               const float* __restrict__ bvb,
                                               unsigned short* __restrict__ kout,
                                               unsigned short* __restrict__ vout){
  __shared__ unsigned short At[128][40];
  __shared__ unsigned short Kt[128][40];
  __shared__ unsigned short Vt[128][40];
  const int t = threadIdx.x, lane = t & 63, wid = t >> 6;
  const int l15 = lane & 15, l4 = lane >> 4;
  const int wr = wid >> 1, wc = wid & 1;
  const int rowBase = blockIdx.y * 128;
  const int colBase = blockIdx.x * 128;
  f32x4 zero = {0.f, 0.f, 0.f, 0.f};
  f32x4 acck[4][4], accv[4][4];
  #pragma unroll
  for (int i = 0; i < 4; ++i)
    #pragma unroll
    for (int j = 0; j < 4; ++j){ acck[i][j] = zero; accv[i][j] = zero; }
  const int sr = t >> 1, sh = (t & 1) * 16;
  for (int ks = 0; ks < 16; ++ks){
    const int k0 = ks * 32;
    const unsigned short* sa = A + (long)(rowBase + sr) * 512 + k0 + sh;
    *(short8*)&At[sr][sh]     = *(const short8*)sa;
    *(short8*)&At[sr][sh + 8] = *(const short8*)(sa + 8);
    const unsigned short* sk = Bk + (long)(colBase + sr) * 512 + k0 + sh;
    *(short8*)&Kt[sr][sh]     = *(const short8*)sk;
    *(short8*)&Kt[sr][sh + 8] = *(const short8*)(sk + 8);
    const unsigned short* sv = Bv + (long)(colBase + sr) * 512 + k0 + sh;
    *(short8*)&Vt[sr][sh]     = *(const short8*)sv;
    *(short8*)&Vt[sr][sh + 8] = *(const short8*)(sv + 8);
    __syncthreads();
    short8 af[4], kf[4], vf[4];
    #pragma unroll
    for (int i = 0; i < 4; ++i) af[i] = *(const short8*)&At[wr*64 + i*16 + l15][l4*8];
    #pragma unroll
    for (int i = 0; i < 4; ++i) kf[i] = *(const short8*)&Kt[wc*64 + i*16 + l15][l4*8];
    #pragma unroll
    for (int i = 0; i < 4; ++i) vf[i] = *(const short8*)&Vt[wc*64 + i*16 + l15][l4*8];
    #pragma unroll
    for (int i = 0; i < 4; ++i)
      #pragma unroll
      for (int j = 0; j < 4; ++j){
        acck[i][j] = mfma16(af[i], kf[j], acck[i][j]);
        accv[i][j] = mfma16(af[i], vf[j], accv[i][j]);
      }
    __syncthreads();
  }
  const long m = blockIdx.y; // 128 rows per block == one music index
  #pragma unroll
  for (int i = 0; i < 4; ++i){
    const int r0 = rowBase + wr*64 + i*16 + l4*4;
    #pragma unroll
    for (int j = 0; j < 4; ++j){
      const int c = colBase + wc*64 + j*16 + l15;
      const float kb = bkb[c], vb = bvb[c];
      #pragma unroll
      for (int jr = 0; jr < 4; ++jr){
        const long rr = r0 + jr;
        kout[rr * 512 + c] = f2bf(acck[i][j][jr] + kb);
        const long s = rr & 127;
        vout[(m * 512 + c) * 128 + s] = f2bf(accv[i][j][jr] + vb);
      }
    }
  }
}

// ---------------- attention: per (m, 32-row q block) ----------------------
__global__ __launch_bounds__(256) void attn_kernel(const unsigned short* __restrict__ q,
                                                   const unsigned short* __restrict__ k,
                                                   const unsigned short* __restrict__ vT,
                                                   const int* __restrict__ mask,
                                                   unsigned short* __restrict__ attn){
  __shared__ __align__(16) char smem[58880];
  unsigned short (*q_lds)[520] = (unsigned short (*)[520])smem;
  unsigned short (*k_lds)[40]  = (unsigned short (*)[40])(smem + 33280);
  float (*lg)[132]             = (float (*)[132])(smem + 33280);
  unsigned short (*w_lds)[136] = (unsigned short (*)[136])(smem + 50176);
  unsigned short (*v_lds)[136] = (unsigned short (*)[136])smem;
  const int m = blockIdx.x >> 3, nb = blockIdx.x & 7;
  const int t = threadIdx.x, lane = t & 63, wid = t >> 6;
  const int l15 = lane & 15, l4 = lane >> 4;
  {
    const int r = t >> 3, c0 = (t & 7) * 64;
    const unsigned short* src = q + (long)(nb*32 + r) * 512 + c0;
    #pragma unroll
    for (int i = 0; i < 64; i += 8)
      *(short8*)&q_lds[r][c0 + i] = *(const short8*)(src + i);
  }
  f32x4 zero = {0.f,0.f,0.f,0.f};
  f32x4 acc[2][2];
  acc[0][0]=zero; acc[0][1]=zero; acc[1][0]=zero; acc[1][1]=zero;
  const int kr = t >> 1, kh = (t & 1) * 16;
  const unsigned short* kbase = k + (long)m * 128 * 512;
  for (int ks = 0; ks < 16; ++ks){
    const int k0 = ks * 32;
    const unsigned short* src = kbase + (long)kr * 512 + k0 + kh;
    *(short8*)&k_lds[kr][kh]     = *(const short8*)src;
    *(short8*)&k_lds[kr][kh + 8] = *(const short8*)(src + 8);
    __syncthreads();
    short8 af[2], bfv[2];
    #pragma unroll
    for (int i = 0; i < 2; ++i) af[i]  = *(const short8*)&q_lds[i*16 + l15][k0 + l4*8];
    #pragma unroll
    for (int i = 0; i < 2; ++i) bfv[i] = *(const short8*)&k_lds[wid*32 + i*16 + l15][l4*8];
    #pragma unroll
    for (int i = 0; i < 2; ++i)
      #pragma unroll
      for (int j = 0; j < 2; ++j)
        acc[i][j] = mfma16(af[i], bfv[j], acc[i][j]);
    __syncthreads();
  }
  const float scale = 0.04419417382415922f; // 1/sqrt(512)
  #pragma unroll
  for (int i = 0; i < 2; ++i)
    #pragma unroll
    for (int j = 0; j < 2; ++j)
      #pragma unroll
      for (int jr = 0; jr < 4; ++jr)
        lg[i*16 + l4*4 + jr][wid*32 + j*16 + l15] = acc[i][j][jr] * scale;
  __syncthreads();
  {
    const int row = t >> 3, u = t & 7;
    const int* mrow = mask + m * 128;
    float vals[16];
    float mx = -3.0e38f;
    #pragma unroll
    for (int i = 0; i < 16; ++i){
      const int s = u*16 + i;
      const float vv = (mrow[s] == 0) ? -3.0e38f : lg[row][s];
      vals[i] = vv;
      mx = fmaxf(mx, vv);
    }
    mx = fmaxf(mx, __shfl_xor(mx, 1));
    mx = fmaxf(mx, __shfl_xor(mx, 2));
    mx = fmaxf(mx, __shfl_xor(mx, 4));
    float sum = 0.f;
    #pragma unroll
    for (int i = 0; i < 16; ++i){
      const float e = __expf(vals[i] - mx);
      vals[i] = e;
      sum += e;
    }
    sum += __shfl_xor(sum, 1);
    sum += __shfl_xor(sum, 2);
    sum += __shfl_xor(sum, 4);
    const float inv = (sum > 0.f) ? (1.f / sum) : 0.f;
    #pragma unroll
    for (int i = 0; i < 16; i += 4){
      u16x4 o = { f2bf(vals[i]*inv), f2bf(vals[i+1]*inv),
                  f2bf(vals[i+2]*inv), f2bf(vals[i+3]*inv) };
      *(u16x4*)&w_lds[row][u*16 + i] = o;
    }
  }
  const long rowb = (long)m * 256 + nb * 32;
  const unsigned short* vbase = vT + (long)m * 512 * 128;
  for (int db = 0; db < 4; ++db){
    __syncthreads();
    {
      const int r = t >> 1, h = (t & 1) * 64;
      const unsigned short* src = vbase + (long)(db*128 + r) * 128 + h;
      #pragma unroll
      for (int i = 0; i < 64; i += 8)
        *(short8*)&v_lds[r][h + i] = *(const short8*)(src + i);
    }
    __syncthreads();
    f32x4 pacc[2][2];
    pacc[0][0]=zero; pacc[0][1]=zero; pacc[1][0]=zero; pacc[1][1]=zero;
    #pragma unroll
    for (int ks2 = 0; ks2 < 4; ++ks2){
      short8 wf[2], vf[2];
      #pragma unroll
      for (int i = 0; i < 2; ++i) wf[i] = *(const short8*)&w_lds[i*16 + l15][ks2*32 + l4*8];
      #pragma unroll
      for (int i = 0; i < 2; ++i) vf[i] = *(const short8*)&v_lds[wid*32 + i*16 + l15][ks2*32 + l4*8];
      #pragma unroll
      for (int i = 0; i < 2; ++i)
        #pragma unroll
        for (int j = 0; j < 2; ++j)
          pacc[i][j] = mfma16(wf[i], vf[j], pacc[i][j]);
    }
    #pragma unroll
    for (int i = 0; i < 2; ++i)
      #pragma unroll
      for (int j = 0; j < 2; ++j)
        #pragma unroll
        for (int jr = 0; jr < 4; ++jr)
          attn[(rowb + i*16 + l4*4 + jr) * 512 + db*128 + wid*32 + j*16 + l15] =
              f2bf(pacc[i][j][jr]);
  }
}

// ---- m97-replica GEMM: C[131072][1024] bf16 = attn[131072][512] * Bcat^T --
// 128x128 tile, 256 thr (2x2 waves), 16KB LDS single-buffer, 2-barrier loop,
// global_load_lds staging with granule-XOR swizzle (R5-verified, 0 conflicts).
__global__ __launch_bounds__(256) void gemm97(const unsigned short* __restrict__ A,
                                              const unsigned short* __restrict__ B,
                                              unsigned short* __restrict__ C){
  __shared__ unsigned short A_lds[4096];   // 128 rows x 4 granules x 8 bf16
  __shared__ unsigned short B_lds[4096];
  const int t = threadIdx.x, lane = t & 63, wid = t >> 6;
  const int l15 = lane & 15, l4 = lane >> 4;
  const int wr = wid >> 1, wc = wid & 1;
  const long rowBase = (long)blockIdx.y * 128;
  const int colBase = blockIdx.x * 128;
  f32x4 zero = {0.f,0.f,0.f,0.f};
  f32x4 acc[4][4];
  #pragma unroll
  for (int i = 0; i < 4; ++i)
    #pragma unroll
    for (int j = 0; j < 4; ++j) acc[i][j] = zero;
  for (int ks = 0; ks < 16; ++ks){
    const int k0 = ks * 32;
    #pragma unroll
    for (int h = 0; h < 2; ++h){
      const int p = h*256 + t;
      const int row = p >> 2, b = (p & 3) ^ ((row >> 1) & 3);
      gload16(A + (rowBase + row)*512 + k0 + b*8, A_lds + p*8);
      gload16(B + (long)(colBase + row)*512 + k0 + b*8, B_lds + p*8);
    }
    __syncthreads();                 // vmcnt drained: tiles visible
    short8 af[4], bfv[4];
    #pragma unroll
    for (int i = 0; i < 4; ++i){
      const int ra = wr*64 + i*16 + l15;
      af[i]  = *(const short8*)(A_lds + (ra*4 + (l4 ^ ((ra >> 1) & 3)))*8);
      const int rb = wc*64 + i*16 + l15;
      bfv[i] = *(const short8*)(B_lds + (rb*4 + (l4 ^ ((rb >> 1) & 3)))*8);
    }
    #pragma unroll
    for (int i = 0; i < 4; ++i)
      #pragma unroll
      for (int j = 0; j < 4; ++j)
        acc[i][j] = mfma16(af[i], bfv[j], acc[i][j]);
    __syncthreads();                 // reads done before next stage
  }
  #pragma unroll
  for (int i = 0; i < 4; ++i){
    const long r0 = rowBase + wr*64 + i*16 + l4*4;
    #pragma unroll
    for (int j = 0; j < 4; ++j){
      const int c = colBase + wc*64 + j*16 + l15;
      #pragma unroll
      for (int jr = 0; jr < 4; ++jr)
        C[(r0 + jr)*1024 + c] = f2bf(acc[i][j][jr]);
    }
  }
}

// ---- LN epilogue, one wave per row, IN-PLACE in d_out --------------------
// C row r (1024 bf16 = 2048B) occupies exactly out row r's bytes (512 f32).
// Per thread: all loads precede all stores -> in-place safe.
// o=C[0:512]+bo; LN2 stats; lin=rstd*(p+c2-mu*u)+v; y=oln+lin; out=LN3(y).
__global__ __launch_bounds__(256) void ln_epilogue(
    const unsigned short* Cb, float* out,   // SAME buffer; no __restrict__
    const float* __restrict__ bias_cat, const float* __restrict__ u,
    const float* __restrict__ v,
    const float* __restrict__ g2, const float* __restrict__ b2,
    const float* __restrict__ g3, const float* __restrict__ b3){
  const int wid = threadIdx.x >> 6, lane = threadIdx.x & 63;
  const long row = (long)blockIdx.x * 4 + wid;
  const unsigned short* cr = Cb + row * 1024;
  short8 ov = *(const short8*)(cr + lane * 8);
  short8 pv = *(const short8*)(cr + 512 + lane * 8);
  const int n0 = lane * 8;
  float4 bo0 = *(const float4*)(bias_cat + n0);
  float4 bo1 = *(const float4*)(bias_cat + n0 + 4);
  float4 c20 = *(const float4*)(bias_cat + 512 + n0);
  float4 c21 = *(const float4*)(bias_cat + 512 + n0 + 4);
  float o[8], p[8];
  #pragma unroll
  for (int j = 0; j < 4; ++j){
    o[j]   = bf2f((unsigned short)ov[j])   + ((const float*)&bo0)[j];
    o[4+j] = bf2f((unsigned short)ov[4+j]) + ((const float*)&bo1)[j];
    p[j]   = bf2f((unsigned short)pv[j])   + ((const float*)&c20)[j];
    p[4+j] = bf2f((unsigned short)pv[4+j]) + ((const float*)&c21)[j];
  }
  float s = 0.f, s2 = 0.f;
  #pragma unroll
  for (int j = 0; j < 8; ++j){ s += o[j]; s2 += o[j]*o[j]; }
  #pragma unroll
  for (int m = 1; m < 64; m <<= 1){ s += __shfl_xor(s, m); s2 += __shfl_xor(s2, m); }
  const float mu2 = s * (1.f/512.f);
  const float rstd2 = rsqrtf(s2 * (1.f/512.f) - mu2*mu2 + 1e-5f);
  float4 uv0 = *(const float4*)(u + n0), uv1 = *(const float4*)(u + n0 + 4);
  float4 vv0 = *(const float4*)(v + n0), vv1 = *(const float4*)(v + n0 + 4);
  float4 g20v = *(const float4*)(g2 + n0), g21v = *(const float4*)(g2 + n0 + 4);
  float4 b20v = *(const float4*)(b2 + n0), b21v = *(const float4*)(b2 + n0 + 4);
  float y[8];
  #pragma unroll
  for (int j = 0; j < 4; ++j){
    const float lin0 = rstd2 * (p[j]   - mu2 * ((const float*)&uv0)[j]) + ((const float*)&vv0)[j];
    const float lin1 = rstd2 * (p[4+j] - mu2 * ((const float*)&uv1)[j]) + ((const float*)&vv1)[j];
    const float oln0 = (o[j]   - mu2) * rstd2 * ((const float*)&g20v)[j] + ((const float*)&b20v)[j];
    const float oln1 = (o[4+j] - mu2) * rstd2 * ((const float*)&g21v)[j] + ((const float*)&b21v)[j];
    y[j]   = oln0 + lin0;
    y[4+j] = oln1 + lin1;
  }
  float t1 = 0.f, t2 = 0.f;
  #pragma unroll
  for (int j = 0; j < 8; ++j){ t1 += y[j]; t2 += y[j]*y[j]; }
  #pragma unroll
  for (int m = 1; m < 64; m <<= 1){ t1 += __shfl_xor(t1, m); t2 += __shfl_xor(t2, m); }
  const float mu3 = t1 * (1.f/512.f);
  const float rstd3 = rsqrtf(t2 * (1.f/512.f) - mu3*mu3 + 1e-5f);
  float4 g30v = *(const float4*)(g3 + n0), g31v = *(const float4*)(g3 + n0 + 4);
  float4 b30v = *(const float4*)(b3 + n0), b31v = *(const float4*)(b3 + n0 + 4);
  float4 r0, r1;
  #pragma unroll
  for (int j = 0; j < 4; ++j){
    ((float*)&r0)[j] = (y[j]   - mu3) * rstd3 * ((const float*)&g30v)[j] + ((const float*)&b30v)[j];
    ((float*)&r1)[j] = (y[4+j] - mu3) * rstd3 * ((const float*)&g31v)[j] + ((const float*)&b31v)[j];
  }
  *(float4*)(out + row * 512 + n0)     = r0;
  *(float4*)(out + row * 512 + n0 + 4) = r1;
}

extern "C" void kernel_launch(void* const* d_in, const int* in_sizes, int n_in,
                              void* d_out, int out_size, void* d_ws, size_t ws_size,
                              hipStream_t stream){
  const float* video = (const float*)d_in[0];
  const float* music = (const float*)d_in[1];
  const int*   mask  = (const int*)d_in[2];
  const float* ln1g  = (const float*)d_in[3];
  const float* ln1b  = (const float*)d_in[4];
  const float* Wq = (const float*)d_in[5];  const float* bq = (const float*)d_in[6];
  const float* Wk = (const float*)d_in[7];  const float* bk = (const float*)d_in[8];
  const float* Wv = (const float*)d_in[9];  const float* bv = (const float*)d_in[10];
  const float* Wo = (const float*)d_in[11]; const float* bo = (const float*)d_in[12];
  const float* Wl = (const float*)d_in[13]; const float* bl = (const float*)d_in[14];
  const float* g2 = (const float*)d_in[15]; const float* b2 = (const float*)d_in[16];
  const float* g3 = (const float*)d_in[17]; const float* b3 = (const float*)d_in[18];

  // d_out scratch: stage-1/2 intermediates, then C (bf16), then final out (in-place)
  char* ob = (char*)d_out;
  unsigned short* mln   = (unsigned short*)ob;                  // [65536][512] bf16
  unsigned short* kbuf  = (unsigned short*)(ob + 67108864);     // [65536][512] bf16
  unsigned short* vTbuf = (unsigned short*)(ob + 134217728);    // [512][512][128] bf16
  unsigned short* Cbuf  = (unsigned short*)ob;                  // [131072][1024] bf16 (full 256MB)
  float* outp = (float*)d_out;

  char* wsb = (char*)d_ws;
  unsigned short* attnb = (unsigned short*)wsb;                 // [131072][512] bf16
  unsigned short* Wq_bf = (unsigned short*)(wsb + 134217728);
  unsigned short* Wk_bf = Wq_bf + 262144;
  unsigned short* Wv_bf = Wk_bf + 262144;
  unsigned short* q_ws  = Wv_bf + 262144;                       // [256][512] bf16
  unsigned short* vln   = q_ws + 131072;                        // [256][512] bf16
  unsigned short* Bcat  = vln + 131072;                         // [1024][512] bf16
  unsigned short* wlp   = Bcat + 524288;                        // [512][512] bf16
  unsigned short* WoT   = wlp + 262144;                         // [512][512] bf16
  float* bias_cat = (float*)(WoT + 262144);                     // [1024]
  float* u_vec    = bias_cat + 1024;                            // [512]
  float* v_vec    = u_vec + 512;                                // [512]

  cvt_f32_bf16<<<256, 256, 0, stream>>>(Wq, Wq_bf);
  cvt_f32_bf16<<<256, 256, 0, stream>>>(Wk, Wk_bf);
  cvt_f32_bf16<<<256, 256, 0, stream>>>(Wv, Wv_bf);
  cvt_f32_bf16<<<256, 256, 0, stream>>>(Wo, Bcat);              // Bcat rows 0..511 = Wo
  ln_weight_prep<<<128, 256, 0, stream>>>(Wl, g2, b2, bl, bo, wlp, u_vec, v_vec, bias_cat);
  transpose_bf<<<dim3(8, 8), 256, 0, stream>>>(Wo, WoT);
  gemm_bt<<<dim3(4, 4), 256, 0, stream>>>(wlp, WoT, nullptr, Bcat + 262144, 0); // W2

  ln_rows<<<16384, 256, 0, stream>>>(music, ln1g, ln1b, mln, 65536);
  ln_rows<<<64,    256, 0, stream>>>(video, ln1g, ln1b, vln, 256);

  gemm_bt<<<dim3(4, 2),   256, 0, stream>>>(vln, Wq_bf, bq, q_ws, 0);
  gemm_kv<<<dim3(4, 512), 256, 0, stream>>>(mln, Wk_bf, bk, Wv_bf, bv, kbuf, vTbuf);

  attn_kernel<<<4096, 256, 0, stream>>>(q_ws, kbuf, vTbuf, mask, attnb);

  // C = attn * Bcat^T  (overwrites mln/kbuf/vTbuf — all dead now)
  gemm97<<<dim3(8, 1024), 256, 0, stream>>>(attnb, Bcat, Cbuf);

  // in-place LN epilogue: C row bytes == out row bytes
  ln_epilogue<<<32768, 256, 0, stream>>>(Cbuf, outp, bias_cat, u_vec, v_vec,
                                         g2, b2, g3, b3);
}

// Round 8
// 740.039 us; speedup vs baseline: 1.2578x; 1.2012x over previous
//
#include <hip/hip_runtime.h>

typedef __attribute__((ext_vector_type(8))) short short8;
typedef __attribute__((ext_vector_type(4))) float f32x4;
typedef __attribute__((ext_vector_type(4))) unsigned short u16x4;

__device__ __forceinline__ unsigned short f2bf(float f){
  unsigned int u = __builtin_bit_cast(unsigned int, f);
  u = (u + 0x7FFFu + ((u >> 16) & 1u)) >> 16;
  return (unsigned short)u;
}
__device__ __forceinline__ float bf2f(unsigned short h){
  unsigned int u = ((unsigned int)h) << 16;
  return __builtin_bit_cast(float, u);
}
__device__ __forceinline__ f32x4 mfma16(short8 a, short8 b, f32x4 c){
  return __builtin_amdgcn_mfma_f32_16x16x32_bf16(a, b, c, 0, 0, 0);
}
// async global->LDS, 16B/lane; lds base wave-uniform (HW: base + lane*16)
__device__ __forceinline__ void gload16(const void* g, void* l){
  __builtin_amdgcn_global_load_lds((const __attribute__((address_space(1))) void*)g,
                                   (__attribute__((address_space(3))) void*)l, 16, 0, 0);
}

// ---------------- f32 -> bf16 conversion (exactly 512*512 elems) ----------
__global__ __launch_bounds__(256) void cvt_f32_bf16(const float* __restrict__ src,
                                                    unsigned short* __restrict__ dst){
  int i = (blockIdx.x * 256 + threadIdx.x) * 4;
  float4 v = *(const float4*)(src + i);
  u16x4 o = { f2bf(v.x), f2bf(v.y), f2bf(v.z), f2bf(v.w) };
  *(u16x4*)(dst + i) = o;
}

// ---------------- LayerNorm over D=512, one wave per row, bf16 out --------
__global__ __launch_bounds__(256) void ln_rows(const float* __restrict__ x,
                                               const float* __restrict__ g,
                                               const float* __restrict__ b,
                                               unsigned short* __restrict__ y,
                                               int nrows){
  const int wid = threadIdx.x >> 6, lane = threadIdx.x & 63;
  const int row = blockIdx.x * 4 + wid;
  if (row >= nrows) return;
  const float* xr = x + (long)row * 512;
  float4 v0 = *(const float4*)(xr + lane * 4);
  float4 v1 = *(const float4*)(xr + 256 + lane * 4);
  float s  = v0.x + v0.y + v0.z + v0.w + v1.x + v1.y + v1.z + v1.w;
  float s2 = v0.x*v0.x + v0.y*v0.y + v0.z*v0.z + v0.w*v0.w
           + v1.x*v1.x + v1.y*v1.y + v1.z*v1.z + v1.w*v1.w;
  #pragma unroll
  for (int m = 1; m < 64; m <<= 1){ s += __shfl_xor(s, m); s2 += __shfl_xor(s2, m); }
  const float mu = s * (1.f/512.f);
  const float rstd = rsqrtf(s2 * (1.f/512.f) - mu*mu + 1e-5f);
  float4 g0 = *(const float4*)(g + lane*4), g1 = *(const float4*)(g + 256 + lane*4);
  float4 b0 = *(const float4*)(b + lane*4), b1 = *(const float4*)(b + 256 + lane*4);
  u16x4 o0 = { f2bf((v0.x-mu)*rstd*g0.x + b0.x), f2bf((v0.y-mu)*rstd*g0.y + b0.y),
               f2bf((v0.z-mu)*rstd*g0.z + b0.z), f2bf((v0.w-mu)*rstd*g0.w + b0.w) };
  u16x4 o1 = { f2bf((v1.x-mu)*rstd*g1.x + b1.x), f2bf((v1.y-mu)*rstd*g1.y + b1.y),
               f2bf((v1.z-mu)*rstd*g1.z + b1.z), f2bf((v1.w-mu)*rstd*g1.w + b1.w) };
  *(u16x4*)(y + (long)row * 512 + lane * 4) = o0;
  *(u16x4*)(y + (long)row * 512 + 256 + lane * 4) = o1;
}

// ---- prep: Wl'[n][c]=Wl[n][c]*g2[c] (bf16); u[n]=sum Wl'; v[n]=Wl.b2+bl;
//      bias_cat[n]=bo[n]; bias_cat[512+n]=c2[n]=sum Wl'[n][c]*bo[c] ---------
__global__ __launch_bounds__(256) void ln_weight_prep(
    const float* __restrict__ Wl, const float* __restrict__ g2,
    const float* __restrict__ b2, const float* __restrict__ bl,
    const float* __restrict__ bo,
    unsigned short* __restrict__ wlp, float* __restrict__ u,
    float* __restrict__ v, float* __restrict__ bias_cat){
  const int wid = threadIdx.x >> 6, lane = threadIdx.x & 63;
  const int n = blockIdx.x * 4 + wid;
  const float* row = Wl + (long)n * 512;
  float su = 0.f, sv = 0.f, sc = 0.f;
  #pragma unroll
  for (int h = 0; h < 2; ++h){
    const int c0 = h * 256 + lane * 4;
    float4 w  = *(const float4*)(row + c0);
    float4 gg = *(const float4*)(g2 + c0);
    float4 bb = *(const float4*)(b2 + c0);
    float4 oo = *(const float4*)(bo + c0);
    float4 wp = { w.x*gg.x, w.y*gg.y, w.z*gg.z, w.w*gg.w };
    su += wp.x + wp.y + wp.z + wp.w;
    sv += w.x*bb.x + w.y*bb.y + w.z*bb.z + w.w*bb.w;
    sc += wp.x*oo.x + wp.y*oo.y + wp.z*oo.z + wp.w*oo.w;
    u16x4 o = { f2bf(wp.x), f2bf(wp.y), f2bf(wp.z), f2bf(wp.w) };
    *(u16x4*)(wlp + (long)n * 512 + c0) = o;
  }
  #pragma unroll
  for (int m = 1; m < 64; m <<= 1){
    su += __shfl_xor(su, m); sv += __shfl_xor(sv, m); sc += __shfl_xor(sc, m);
  }
  if (lane == 0){
    u[n] = su;
    v[n] = sv + bl[n];
    bias_cat[n] = bo[n];
    bias_cat[512 + n] = sc;
  }
}

// ---- transpose 512x512: dst[k][c] = bf16(src[c][k]) ----------------------
__global__ __launch_bounds__(256) void transpose_bf(const float* __restrict__ src,
                                                    unsigned short* __restrict__ dst){
  __shared__ float tile[64][65];
  const int t = threadIdx.x;
  const int k0 = blockIdx.x * 64, c0 = blockIdx.y * 64;
  const int j = t & 63, i = t >> 6;
  #pragma unroll
  for (int rr = 0; rr < 16; ++rr)
    tile[i + rr*4][j] = src[(long)(c0 + i + rr*4) * 512 + k0 + j];
  __syncthreads();
  #pragma unroll
  for (int rr = 0; rr < 16; ++rr)
    dst[(long)(k0 + i + rr*4) * 512 + c0 + j] = f2bf(tile[j][i + rr*4]);
}

// ---------------- C = A(rows x 512) * B(512 x 512)^T + bias ---------------
__global__ __launch_bounds__(256) void gemm_bt(const unsigned short* __restrict__ A,
                                               const unsigned short* __restrict__ B,
                                               const float* __restrict__ bias,
                                               unsigned short* __restrict__ out,
                                               int transposed){
  __shared__ unsigned short At[128][40];
  __shared__ unsigned short Bt[128][40];
  const int t = threadIdx.x, lane = t & 63, wid = t >> 6;
  const int l15 = lane & 15, l4 = lane >> 4;
  const int wr = wid >> 1, wc = wid & 1;
  const int rowBase = blockIdx.y * 128;
  const int colBase = blockIdx.x * 128;
  f32x4 zero = {0.f, 0.f, 0.f, 0.f};
  f32x4 acc[4][4];
  #pragma unroll
  for (int i = 0; i < 4; ++i)
    #pragma unroll
    for (int j = 0; j < 4; ++j) acc[i][j] = zero;
  const int sr = t >> 1, sh = (t & 1) * 16;
  for (int ks = 0; ks < 16; ++ks){
    const int k0 = ks * 32;
    const unsigned short* sa = A + (long)(rowBase + sr) * 512 + k0 + sh;
    *(short8*)&At[sr][sh]     = *(const short8*)sa;
    *(short8*)&At[sr][sh + 8] = *(const short8*)(sa + 8);
    const unsigned short* sb = B + (long)(colBase + sr) * 512 + k0 + sh;
    *(short8*)&Bt[sr][sh]     = *(const short8*)sb;
    *(short8*)&Bt[sr][sh + 8] = *(const short8*)(sb + 8);
    __syncthreads();
    short8 af[4], bfv[4];
    #pragma unroll
    for (int i = 0; i < 4; ++i) af[i]  = *(const short8*)&At[wr*64 + i*16 + l15][l4*8];
    #pragma unroll
    for (int i = 0; i < 4; ++i) bfv[i] = *(const short8*)&Bt[wc*64 + i*16 + l15][l4*8];
    #pragma unroll
    for (int i = 0; i < 4; ++i)
      #pragma unroll
      for (int j = 0; j < 4; ++j)
        acc[i][j] = mfma16(af[i], bfv[j], acc[i][j]);
    __syncthreads();
  }
  #pragma unroll
  for (int i = 0; i < 4; ++i){
    const int r0 = rowBase + wr*64 + i*16 + l4*4;
    #pragma unroll
    for (int j = 0; j < 4; ++j){
      const int c = colBase + wc*64 + j*16 + l15;
      const float bb = bias ? bias[c] : 0.f;
      #pragma unroll
      for (int jr = 0; jr < 4; ++jr){
        const float v = acc[i][j][jr] + bb;
        const long rr = r0 + jr;
        if (!transposed){
          out[rr * 512 + c] = f2bf(v);
        } else {
          const long m = rr >> 7, s = rr & 127;
          out[(m * 512 + c) * 128 + s] = f2bf(v);
        }
      }
    }
  }
}

// ---- K,V projection, gemm97 structure: C[65536][1024] = mln * [Wk;Wv]^T --
// XCD-panel swizzle: 8 col-blocks of one A-panel on one XCD (A-panel L2-hot).
// Col half 0..511 -> K (row-major + bk); 512..1023 -> V (transposed + bv).
__global__ __launch_bounds__(256) void gemm_kv97(const unsigned short* __restrict__ A,
                                                 const unsigned short* __restrict__ B,
                                                 const float* __restrict__ bk,
                                                 const float* __restrict__ bv,
                                                 unsigned short* __restrict__ kout,
                                                 unsigned short* __restrict__ vout){
  __shared__ unsigned short A_lds[4096];
  __shared__ unsigned short B_lds[4096];
  const int t = threadIdx.x, lane = t & 63, wid = t >> 6;
  const int l15 = lane & 15, l4 = lane >> 4;
  const int wr = wid >> 1, wc = wid & 1;
  const int b = blockIdx.x;               // 4096 blocks
  const int kk = b >> 3;
  const int colBase = (kk & 7) * 128;
  const long panel = (b & 7) + 8 * (kk >> 3);   // 0..511 (music index m)
  const long rowBase = panel * 128;
  f32x4 zero = {0.f,0.f,0.f,0.f};
  f32x4 acc[4][4];
  #pragma unroll
  for (int i = 0; i < 4; ++i)
    #pragma unroll
    for (int j = 0; j < 4; ++j) acc[i][j] = zero;
  for (int ks = 0; ks < 16; ++ks){
    const int k0 = ks * 32;
    #pragma unroll
    for (int h = 0; h < 2; ++h){
      const int p = h*256 + t;
      const int row = p >> 2, g = (p & 3) ^ ((row >> 1) & 3);
      gload16(A + (rowBase + row)*512 + k0 + g*8, A_lds + p*8);
      gload16(B + (long)(colBase + row)*512 + k0 + g*8, B_lds + p*8);
    }
    __syncthreads();
    short8 af[4], bfv[4];
    #pragma unroll
    for (int i = 0; i < 4; ++i){
      const int ra = wr*64 + i*16 + l15;
      af[i]  = *(const short8*)(A_lds + (ra*4 + (l4 ^ ((ra >> 1) & 3)))*8);
      const int rb = wc*64 + i*16 + l15;
      bfv[i] = *(const short8*)(B_lds + (rb*4 + (l4 ^ ((rb >> 1) & 3)))*8);
    }
    #pragma unroll
    for (int i = 0; i < 4; ++i)
      #pragma unroll
      for (int j = 0; j < 4; ++j)
        acc[i][j] = mfma16(af[i], bfv[j], acc[i][j]);
    __syncthreads();
  }
  if (colBase < 512){
    #pragma unroll
    for (int i = 0; i < 4; ++i){
      const long r0 = rowBase + wr*64 + i*16 + l4*4;
      #pragma unroll
      for (int j = 0; j < 4; ++j){
        const int c = colBase + wc*64 + j*16 + l15;
        const float bb = bk[c];
        #pragma unroll
        for (int jr = 0; jr < 4; ++jr)
          kout[(r0 + jr)*512 + c] = f2bf(acc[i][j][jr] + bb);
      }
    }
  } else {
    #pragma unroll
    for (int i = 0; i < 4; ++i){
      const int s0 = wr*64 + i*16 + l4*4;
      #pragma unroll
      for (int j = 0; j < 4; ++j){
        const int d = colBase - 512 + wc*64 + j*16 + l15;
        const float bb = bv[d];
        #pragma unroll
        for (int jr = 0; jr < 4; ++jr)
          vout[(panel*512 + d)*128 + s0 + jr] = f2bf(acc[i][j][jr] + bb);
      }
    }
  }
}

// ---------------- attention: per (m, 32-row q block), XCD-swizzled --------
__global__ __launch_bounds__(256) void attn_kernel(const unsigned short* __restrict__ q,
                                                   const unsigned short* __restrict__ k,
                                                   const unsigned short* __restrict__ vT,
                                                   const int* __restrict__ mask,
                                                   unsigned short* __restrict__ attn){
  __shared__ __align__(16) char smem[58880];
  unsigned short (*q_lds)[520] = (unsigned short (*)[520])smem;
  unsigned short (*k_lds)[40]  = (unsigned short (*)[40])(smem + 33280);
  float (*lg)[132]             = (float (*)[132])(smem + 33280);
  unsigned short (*w_lds)[136] = (unsigned short (*)[136])(smem + 50176);
  unsigned short (*v_lds)[136] = (unsigned short (*)[136])smem;
  const int bq = blockIdx.x;
  const int m = (bq & 7) + 8 * ((bq >> 3) >> 3);   // same-XCD blocks share m
  const int nb = (bq >> 3) & 7;
  const int t = threadIdx.x, lane = t & 63, wid = t >> 6;
  const int l15 = lane & 15, l4 = lane >> 4;
  {
    const int r = t >> 3, c0 = (t & 7) * 64;
    const unsigned short* src = q + (long)(nb*32 + r) * 512 + c0;
    #pragma unroll
    for (int i = 0; i < 64; i += 8)
      *(short8*)&q_lds[r][c0 + i] = *(const short8*)(src + i);
  }
  f32x4 zero = {0.f,0.f,0.f,0.f};
  f32x4 acc[2][2];
  acc[0][0]=zero; acc[0][1]=zero; acc[1][0]=zero; acc[1][1]=zero;
  const int kr = t >> 1, kh = (t & 1) * 16;
  const unsigned short* kbase = k + (long)m * 128 * 512;
  for (int ks = 0; ks < 16; ++ks){
    const int k0 = ks * 32;
    const unsigned short* src = kbase + (long)kr * 512 + k0 + kh;
    *(short8*)&k_lds[kr][kh]     = *(const short8*)src;
    *(short8*)&k_lds[kr][kh + 8] = *(const short8*)(src + 8);
    __syncthreads();
    short8 af[2], bfv[2];
    #pragma unroll
    for (int i = 0; i < 2; ++i) af[i]  = *(const short8*)&q_lds[i*16 + l15][k0 + l4*8];
    #pragma unroll
    for (int i = 0; i < 2; ++i) bfv[i] = *(const short8*)&k_lds[wid*32 + i*16 + l15][l4*8];
    #pragma unroll
    for (int i = 0; i < 2; ++i)
      #pragma unroll
      for (int j = 0; j < 2; ++j)
        acc[i][j] = mfma16(af[i], bfv[j], acc[i][j]);
    __syncthreads();
  }
  const float scale = 0.04419417382415922f; // 1/sqrt(512)
  #pragma unroll
  for (int i = 0; i < 2; ++i)
    #pragma unroll
    for (int j = 0; j < 2; ++j)
      #pragma unroll
      for (int jr = 0; jr < 4; ++jr)
        lg[i*16 + l4*4 + jr][wid*32 + j*16 + l15] = acc[i][j][jr] * scale;
  __syncthreads();
  {
    const int row = t >> 3, u = t & 7;
    const int* mrow = mask + m * 128;
    float vals[16];
    float mx = -3.0e38f;
    #pragma unroll
    for (int i = 0; i < 16; ++i){
      const int s = u*16 + i;
      const float vv = (mrow[s] == 0) ? -3.0e38f : lg[row][s];
      vals[i] = vv;
      mx = fmaxf(mx, vv);
    }
    mx = fmaxf(mx, __shfl_xor(mx, 1));
    mx = fmaxf(mx, __shfl_xor(mx, 2));
    mx = fmaxf(mx, __shfl_xor(mx, 4));
    float sum = 0.f;
    #pragma unroll
    for (int i = 0; i < 16; ++i){
      const float e = __expf(vals[i] - mx);
      vals[i] = e;
      sum += e;
    }
    sum += __shfl_xor(sum, 1);
    sum += __shfl_xor(sum, 2);
    sum += __shfl_xor(sum, 4);
    const float inv = (sum > 0.f) ? (1.f / sum) : 0.f;
    #pragma unroll
    for (int i = 0; i < 16; i += 4){
      u16x4 o = { f2bf(vals[i]*inv), f2bf(vals[i+1]*inv),
                  f2bf(vals[i+2]*inv), f2bf(vals[i+3]*inv) };
      *(u16x4*)&w_lds[row][u*16 + i] = o;
    }
  }
  const long rowb = (long)m * 256 + nb * 32;
  const unsigned short* vbase = vT + (long)m * 512 * 128;
  for (int db = 0; db < 4; ++db){
    __syncthreads();
    {
      const int r = t >> 1, h = (t & 1) * 64;
      const unsigned short* src = vbase + (long)(db*128 + r) * 128 + h;
      #pragma unroll
      for (int i = 0; i < 64; i += 8)
        *(short8*)&v_lds[r][h + i] = *(const short8*)(src + i);
    }
    __syncthreads();
    f32x4 pacc[2][2];
    pacc[0][0]=zero; pacc[0][1]=zero; pacc[1][0]=zero; pacc[1][1]=zero;
    #pragma unroll
    for (int ks2 = 0; ks2 < 4; ++ks2){
      short8 wf[2], vf[2];
      #pragma unroll
      for (int i = 0; i < 2; ++i) wf[i] = *(const short8*)&w_lds[i*16 + l15][ks2*32 + l4*8];
      #pragma unroll
      for (int i = 0; i < 2; ++i) vf[i] = *(const short8*)&v_lds[wid*32 + i*16 + l15][ks2*32 + l4*8];
      #pragma unroll
      for (int i = 0; i < 2; ++i)
        #pragma unroll
        for (int j = 0; j < 2; ++j)
          pacc[i][j] = mfma16(wf[i], vf[j], pacc[i][j]);
    }
    #pragma unroll
    for (int i = 0; i < 2; ++i)
      #pragma unroll
      for (int j = 0; j < 2; ++j)
        #pragma unroll
        for (int jr = 0; jr < 4; ++jr)
          attn[(rowb + i*16 + l4*4 + jr) * 512 + db*128 + wid*32 + j*16 + l15] =
              f2bf(pacc[i][j][jr]);
  }
}

// ---- m97-replica GEMM: C[131072][1024] bf16 = attn[131072][512] * Bcat^T --
// XCD-panel swizzle: the 8 col-blocks of one A-panel run on ONE XCD, so the
// A-panel (128KB) + whole B (1MB) stay L2-resident per XCD.
__global__ __launch_bounds__(256) void gemm97(const unsigned short* __restrict__ A,
                                              const unsigned short* __restrict__ B,
                                              unsigned short* __restrict__ C){
  __shared__ unsigned short A_lds[4096];   // 128 rows x 4 granules x 8 bf16
  __shared__ unsigned short B_lds[4096];
  const int t = threadIdx.x, lane = t & 63, wid = t >> 6;
  const int l15 = lane & 15, l4 = lane >> 4;
  const int wr = wid >> 1, wc = wid & 1;
  const int b = blockIdx.x;               // 8192 blocks
  const int kk = b >> 3;
  const int colBase = (kk & 7) * 128;
  const long rowBase = ((long)(b & 7) + 8 * (kk >> 3)) * 128;   // panel-swizzled
  f32x4 zero = {0.f,0.f,0.f,0.f};
  f32x4 acc[4][4];
  #pragma unroll
  for (int i = 0; i < 4; ++i)
    #pragma unroll
    for (int j = 0; j < 4; ++j) acc[i][j] = zero;
  for (int ks = 0; ks < 16; ++ks){
    const int k0 = ks * 32;
    #pragma unroll
    for (int h = 0; h < 2; ++h){
      const int p = h*256 + t;
      const int row = p >> 2, g = (p & 3) ^ ((row >> 1) & 3);
      gload16(A + (rowBase + row)*512 + k0 + g*8, A_lds + p*8);
      gload16(B + (long)(colBase + row)*512 + k0 + g*8, B_lds + p*8);
    }
    __syncthreads();                 // vmcnt drained: tiles visible
    short8 af[4], bfv[4];
    #pragma unroll
    for (int i = 0; i < 4; ++i){
      const int ra = wr*64 + i*16 + l15;
      af[i]  = *(const short8*)(A_lds + (ra*4 + (l4 ^ ((ra >> 1) & 3)))*8);
      const int rb = wc*64 + i*16 + l15;
      bfv[i] = *(const short8*)(B_lds + (rb*4 + (l4 ^ ((rb >> 1) & 3)))*8);
    }
    #pragma unroll
    for (int i = 0; i < 4; ++i)
      #pragma unroll
      for (int j = 0; j < 4; ++j)
        acc[i][j] = mfma16(af[i], bfv[j], acc[i][j]);
    __syncthreads();                 // reads done before next stage
  }
  #pragma unroll
  for (int i = 0; i < 4; ++i){
    const long r0 = rowBase + wr*64 + i*16 + l4*4;
    #pragma unroll
    for (int j = 0; j < 4; ++j){
      const int c = colBase + wc*64 + j*16 + l15;
      #pragma unroll
      for (int jr = 0; jr < 4; ++jr)
        C[(r0 + jr)*1024 + c] = f2bf(acc[i][j][jr]);
    }
  }
}

// ---- LN epilogue, one wave per row, IN-PLACE in d_out --------------------
__global__ __launch_bounds__(256) void ln_epilogue(
    const unsigned short* Cb, float* out,   // SAME buffer; no __restrict__
    const float* __restrict__ bias_cat, const float* __restrict__ u,
    const float* __restrict__ v,
    const float* __restrict__ g2, const float* __restrict__ b2,
    const float* __restrict__ g3, const float* __restrict__ b3){
  const int wid = threadIdx.x >> 6, lane = threadIdx.x & 63;
  const long row = (long)blockIdx.x * 4 + wid;
  const unsigned short* cr = Cb + row * 1024;
  short8 ov = *(const short8*)(cr + lane * 8);
  short8 pv = *(const short8*)(cr + 512 + lane * 8);
  const int n0 = lane * 8;
  float4 bo0 = *(const float4*)(bias_cat + n0);
  float4 bo1 = *(const float4*)(bias_cat + n0 + 4);
  float4 c20 = *(const float4*)(bias_cat + 512 + n0);
  float4 c21 = *(const float4*)(bias_cat + 512 + n0 + 4);
  float o[8], p[8];
  #pragma unroll
  for (int j = 0; j < 4; ++j){
    o[j]   = bf2f((unsigned short)ov[j])   + ((const float*)&bo0)[j];
    o[4+j] = bf2f((unsigned short)ov[4+j]) + ((const float*)&bo1)[j];
    p[j]   = bf2f((unsigned short)pv[j])   + ((const float*)&c20)[j];
    p[4+j] = bf2f((unsigned short)pv[4+j]) + ((const float*)&c21)[j];
  }
  float s = 0.f, s2 = 0.f;
  #pragma unroll
  for (int j = 0; j < 8; ++j){ s += o[j]; s2 += o[j]*o[j]; }
  #pragma unroll
  for (int m = 1; m < 64; m <<= 1){ s += __shfl_xor(s, m); s2 += __shfl_xor(s2, m); }
  const float mu2 = s * (1.f/512.f);
  const float rstd2 = rsqrtf(s2 * (1.f/512.f) - mu2*mu2 + 1e-5f);
  float4 uv0 = *(const float4*)(u + n0), uv1 = *(const float4*)(u + n0 + 4);
  float4 vv0 = *(const float4*)(v + n0), vv1 = *(const float4*)(v + n0 + 4);
  float4 g20v = *(const float4*)(g2 + n0), g21v = *(const float4*)(g2 + n0 + 4);
  float4 b20v = *(const float4*)(b2 + n0), b21v = *(const float4*)(b2 + n0 + 4);
  float y[8];
  #pragma unroll
  for (int j = 0; j < 4; ++j){
    const float lin0 = rstd2 * (p[j]   - mu2 * ((const float*)&uv0)[j]) + ((const float*)&vv0)[j];
    const float lin1 = rstd2 * (p[4+j] - mu2 * ((const float*)&uv1)[j]) + ((const float*)&vv1)[j];
    const float oln0 = (o[j]   - mu2) * rstd2 * ((const float*)&g20v)[j] + ((const float*)&b20v)[j];
    const float oln1 = (o[4+j] - mu2) * rstd2 * ((const float*)&g21v)[j] + ((const float*)&b21v)[j];
    y[j]   = oln0 + lin0;
    y[4+j] = oln1 + lin1;
  }
  float t1 = 0.f, t2 = 0.f;
  #pragma unroll
  for (int j = 0; j < 8; ++j){ t1 += y[j]; t2 += y[j]*y[j]; }
  #pragma unroll
  for (int m = 1; m < 64; m <<= 1){ t1 += __shfl_xor(t1, m); t2 += __shfl_xor(t2, m); }
  const float mu3 = t1 * (1.f/512.f);
  const float rstd3 = rsqrtf(t2 * (1.f/512.f) - mu3*mu3 + 1e-5f);
  float4 g30v = *(const float4*)(g3 + n0), g31v = *(const float4*)(g3 + n0 + 4);
  float4 b30v = *(const float4*)(b3 + n0), b31v = *(const float4*)(b3 + n0 + 4);
  float4 r0, r1;
  #pragma unroll
  for (int j = 0; j < 4; ++j){
    ((float*)&r0)[j] = (y[j]   - mu3) * rstd3 * ((const float*)&g30v)[j] + ((const float*)&b30v)[j];
    ((float*)&r1)[j] = (y[4+j] - mu3) * rstd3 * ((const float*)&g31v)[j] + ((const float*)&b31v)[j];
  }
  *(float4*)(out + row * 512 + n0)     = r0;
  *(float4*)(out + row * 512 + n0 + 4) = r1;
}

extern "C" void kernel_launch(void* const* d_in, const int* in_sizes, int n_in,
                              void* d_out, int out_size, void* d_ws, size_t ws_size,
                              hipStream_t stream){
  const float* video = (const float*)d_in[0];
  const float* music = (const float*)d_in[1];
  const int*   mask  = (const int*)d_in[2];
  const float* ln1g  = (const float*)d_in[3];
  const float* ln1b  = (const float*)d_in[4];
  const float* Wq = (const float*)d_in[5];  const float* bq = (const float*)d_in[6];
  const float* Wk = (const float*)d_in[7];  const float* bk = (const float*)d_in[8];
  const float* Wv = (const float*)d_in[9];  const float* bv = (const float*)d_in[10];
  const float* Wo = (const float*)d_in[11]; const float* bo = (const float*)d_in[12];
  const float* Wl = (const float*)d_in[13]; const float* bl = (const float*)d_in[14];
  const float* g2 = (const float*)d_in[15]; const float* b2 = (const float*)d_in[16];
  const float* g3 = (const float*)d_in[17]; const float* b3 = (const float*)d_in[18];

  // d_out scratch: stage-1/2 intermediates, then C (bf16), then final out (in-place)
  char* ob = (char*)d_out;
  unsigned short* mln   = (unsigned short*)ob;                  // [65536][512] bf16
  unsigned short* kbuf  = (unsigned short*)(ob + 67108864);     // [65536][512] bf16
  unsigned short* vTbuf = (unsigned short*)(ob + 134217728);    // [512][512][128] bf16
  unsigned short* Cbuf  = (unsigned short*)ob;                  // [131072][1024] bf16
  float* outp = (float*)d_out;

  char* wsb = (char*)d_ws;
  unsigned short* attnb = (unsigned short*)wsb;                 // [131072][512] bf16
  unsigned short* Wq_bf = (unsigned short*)(wsb + 134217728);
  unsigned short* KVcat = Wq_bf + 262144;                       // [1024][512]: Wk rows 0..511, Wv rows 512..1023
  unsigned short* q_ws  = KVcat + 524288;                       // [256][512] bf16
  unsigned short* vln   = q_ws + 131072;                        // [256][512] bf16
  unsigned short* Bcat  = vln + 131072;                         // [1024][512] bf16
  unsigned short* wlp   = Bcat + 524288;                        // [512][512] bf16
  unsigned short* WoT   = wlp + 262144;                         // [512][512] bf16
  float* bias_cat = (float*)(WoT + 262144);                     // [1024]
  float* u_vec    = bias_cat + 1024;                            // [512]
  float* v_vec    = u_vec + 512;                                // [512]

  cvt_f32_bf16<<<256, 256, 0, stream>>>(Wq, Wq_bf);
  cvt_f32_bf16<<<256, 256, 0, stream>>>(Wk, KVcat);
  cvt_f32_bf16<<<256, 256, 0, stream>>>(Wv, KVcat + 262144);
  cvt_f32_bf16<<<256, 256, 0, stream>>>(Wo, Bcat);              // Bcat rows 0..511 = Wo
  ln_weight_prep<<<128, 256, 0, stream>>>(Wl, g2, b2, bl, bo, wlp, u_vec, v_vec, bias_cat);
  transpose_bf<<<dim3(8, 8), 256, 0, stream>>>(Wo, WoT);
  gemm_bt<<<dim3(4, 4), 256, 0, stream>>>(wlp, WoT, nullptr, Bcat + 262144, 0); // W2

  ln_rows<<<16384, 256, 0, stream>>>(music, ln1g, ln1b, mln, 65536);
  ln_rows<<<64,    256, 0, stream>>>(video, ln1g, ln1b, vln, 256);

  gemm_bt<<<dim3(4, 2), 256, 0, stream>>>(vln, Wq_bf, bq, q_ws, 0);
  gemm_kv97<<<4096, 256, 0, stream>>>(mln, KVcat, bk, bv, kbuf, vTbuf);

  attn_kernel<<<4096, 256, 0, stream>>>(q_ws, kbuf, vTbuf, mask, attnb);

  // C = attn * Bcat^T  (overwrites mln/kbuf/vTbuf — all dead now)
  gemm97<<<8192, 256, 0, stream>>>(attnb, Bcat, Cbuf);

  // in-place LN epilogue: C row bytes == out row bytes
  ln_epilogue<<<32768, 256, 0, stream>>>(Cbuf, outp, bias_cat, u_vec, v_vec,
                                         g2, b2, g3, b3);
}

// Round 9
// 682.842 us; speedup vs baseline: 1.3631x; 1.0838x over previous
//
#include <hip/hip_runtime.h>

typedef __attribute__((ext_vector_type(8))) short short8;
typedef __attribute__((ext_vector_type(4))) float f32x4;
typedef __attribute__((ext_vector_type(4))) unsigned short u16x4;

__device__ __forceinline__ unsigned short f2bf(float f){
  unsigned int u = __builtin_bit_cast(unsigned int, f);
  u = (u + 0x7FFFu + ((u >> 16) & 1u)) >> 16;
  return (unsigned short)u;
}
__device__ __forceinline__ float bf2f(unsigned short h){
  unsigned int u = ((unsigned int)h) << 16;
  return __builtin_bit_cast(float, u);
}
__device__ __forceinline__ f32x4 mfma16(short8 a, short8 b, f32x4 c){
  return __builtin_amdgcn_mfma_f32_16x16x32_bf16(a, b, c, 0, 0, 0);
}
// async global->LDS, 16B/lane; lds base wave-uniform (HW: base + lane*16)
__device__ __forceinline__ void gload16(const void* g, void* l){
  __builtin_amdgcn_global_load_lds((const __attribute__((address_space(1))) void*)g,
                                   (__attribute__((address_space(3))) void*)l, 16, 0, 0);
}

// ---------------- f32 -> bf16 conversion (exactly 512*512 elems) ----------
__global__ __launch_bounds__(256) void cvt_f32_bf16(const float* __restrict__ src,
                                                    unsigned short* __restrict__ dst){
  int i = (blockIdx.x * 256 + threadIdx.x) * 4;
  float4 v = *(const float4*)(src + i);
  u16x4 o = { f2bf(v.x), f2bf(v.y), f2bf(v.z), f2bf(v.w) };
  *(u16x4*)(dst + i) = o;
}

// ---------------- LayerNorm over D=512, one wave per row, bf16 out --------
__global__ __launch_bounds__(256) void ln_rows(const float* __restrict__ x,
                                               const float* __restrict__ g,
                                               const float* __restrict__ b,
                                               unsigned short* __restrict__ y,
                                               int nrows){
  const int wid = threadIdx.x >> 6, lane = threadIdx.x & 63;
  const int row = blockIdx.x * 4 + wid;
  if (row >= nrows) return;
  const float* xr = x + (long)row * 512;
  float4 v0 = *(const float4*)(xr + lane * 4);
  float4 v1 = *(const float4*)(xr + 256 + lane * 4);
  float s  = v0.x + v0.y + v0.z + v0.w + v1.x + v1.y + v1.z + v1.w;
  float s2 = v0.x*v0.x + v0.y*v0.y + v0.z*v0.z + v0.w*v0.w
           + v1.x*v1.x + v1.y*v1.y + v1.z*v1.z + v1.w*v1.w;
  #pragma unroll
  for (int m = 1; m < 64; m <<= 1){ s += __shfl_xor(s, m); s2 += __shfl_xor(s2, m); }
  const float mu = s * (1.f/512.f);
  const float rstd = rsqrtf(s2 * (1.f/512.f) - mu*mu + 1e-5f);
  float4 g0 = *(const float4*)(g + lane*4), g1 = *(const float4*)(g + 256 + lane*4);
  float4 b0 = *(const float4*)(b + lane*4), b1 = *(const float4*)(b + 256 + lane*4);
  u16x4 o0 = { f2bf((v0.x-mu)*rstd*g0.x + b0.x), f2bf((v0.y-mu)*rstd*g0.y + b0.y),
               f2bf((v0.z-mu)*rstd*g0.z + b0.z), f2bf((v0.w-mu)*rstd*g0.w + b0.w) };
  u16x4 o1 = { f2bf((v1.x-mu)*rstd*g1.x + b1.x), f2bf((v1.y-mu)*rstd*g1.y + b1.y),
               f2bf((v1.z-mu)*rstd*g1.z + b1.z), f2bf((v1.w-mu)*rstd*g1.w + b1.w) };
  *(u16x4*)(y + (long)row * 512 + lane * 4) = o0;
  *(u16x4*)(y + (long)row * 512 + 256 + lane * 4) = o1;
}

// ---- prep: Wl'[n][c]=Wl[n][c]*g2[c] (bf16); u[n]=sum Wl'; v[n]=Wl.b2+bl;
//      bias_cat[n]=bo[n]; bias_cat[512+n]=c2[n]=sum Wl'[n][c]*bo[c] ---------
__global__ __launch_bounds__(256) void ln_weight_prep(
    const float* __restrict__ Wl, const float* __restrict__ g2,
    const float* __restrict__ b2, const float* __restrict__ bl,
    const float* __restrict__ bo,
    unsigned short* __restrict__ wlp, float* __restrict__ u,
    float* __restrict__ v, float* __restrict__ bias_cat){
  const int wid = threadIdx.x >> 6, lane = threadIdx.x & 63;
  const int n = blockIdx.x * 4 + wid;
  const float* row = Wl + (long)n * 512;
  float su = 0.f, sv = 0.f, sc = 0.f;
  #pragma unroll
  for (int h = 0; h < 2; ++h){
    const int c0 = h * 256 + lane * 4;
    float4 w  = *(const float4*)(row + c0);
    float4 gg = *(const float4*)(g2 + c0);
    float4 bb = *(const float4*)(b2 + c0);
    float4 oo = *(const float4*)(bo + c0);
    float4 wp = { w.x*gg.x, w.y*gg.y, w.z*gg.z, w.w*gg.w };
    su += wp.x + wp.y + wp.z + wp.w;
    sv += w.x*bb.x + w.y*bb.y + w.z*bb.z + w.w*bb.w;
    sc += wp.x*oo.x + wp.y*oo.y + wp.z*oo.z + wp.w*oo.w;
    u16x4 o = { f2bf(wp.x), f2bf(wp.y), f2bf(wp.z), f2bf(wp.w) };
    *(u16x4*)(wlp + (long)n * 512 + c0) = o;
  }
  #pragma unroll
  for (int m = 1; m < 64; m <<= 1){
    su += __shfl_xor(su, m); sv += __shfl_xor(sv, m); sc += __shfl_xor(sc, m);
  }
  if (lane == 0){
    u[n] = su;
    v[n] = sv + bl[n];
    bias_cat[n] = bo[n];
    bias_cat[512 + n] = sc;
  }
}

// ---- transpose 512x512: dst[k][c] = bf16(src[c][k]) ----------------------
__global__ __launch_bounds__(256) void transpose_bf(const float* __restrict__ src,
                                                    unsigned short* __restrict__ dst){
  __shared__ float tile[64][65];
  const int t = threadIdx.x;
  const int k0 = blockIdx.x * 64, c0 = blockIdx.y * 64;
  const int j = t & 63, i = t >> 6;
  #pragma unroll
  for (int rr = 0; rr < 16; ++rr)
    tile[i + rr*4][j] = src[(long)(c0 + i + rr*4) * 512 + k0 + j];
  __syncthreads();
  #pragma unroll
  for (int rr = 0; rr < 16; ++rr)
    dst[(long)(k0 + i + rr*4) * 512 + c0 + j] = f2bf(tile[j][i + rr*4]);
}

// ---------------- C = A(rows x 512) * B(512 x 512)^T + bias ---------------
__global__ __launch_bounds__(256) void gemm_bt(const unsigned short* __restrict__ A,
                                               const unsigned short* __restrict__ B,
                                               const float* __restrict__ bias,
                                               unsigned short* __restrict__ out,
                                               int transposed){
  __shared__ unsigned short At[128][40];
  __shared__ unsigned short Bt[128][40];
  const int t = threadIdx.x, lane = t & 63, wid = t >> 6;
  const int l15 = lane & 15, l4 = lane >> 4;
  const int wr = wid >> 1, wc = wid & 1;
  const int rowBase = blockIdx.y * 128;
  const int colBase = blockIdx.x * 128;
  f32x4 zero = {0.f, 0.f, 0.f, 0.f};
  f32x4 acc[4][4];
  #pragma unroll
  for (int i = 0; i < 4; ++i)
    #pragma unroll
    for (int j = 0; j < 4; ++j) acc[i][j] = zero;
  const int sr = t >> 1, sh = (t & 1) * 16;
  for (int ks = 0; ks < 16; ++ks){
    const int k0 = ks * 32;
    const unsigned short* sa = A + (long)(rowBase + sr) * 512 + k0 + sh;
    *(short8*)&At[sr][sh]     = *(const short8*)sa;
    *(short8*)&At[sr][sh + 8] = *(const short8*)(sa + 8);
    const unsigned short* sb = B + (long)(colBase + sr) * 512 + k0 + sh;
    *(short8*)&Bt[sr][sh]     = *(const short8*)sb;
    *(short8*)&Bt[sr][sh + 8] = *(const short8*)(sb + 8);
    __syncthreads();
    short8 af[4], bfv[4];
    #pragma unroll
    for (int i = 0; i < 4; ++i) af[i]  = *(const short8*)&At[wr*64 + i*16 + l15][l4*8];
    #pragma unroll
    for (int i = 0; i < 4; ++i) bfv[i] = *(const short8*)&Bt[wc*64 + i*16 + l15][l4*8];
    #pragma unroll
    for (int i = 0; i < 4; ++i)
      #pragma unroll
      for (int j = 0; j < 4; ++j)
        acc[i][j] = mfma16(af[i], bfv[j], acc[i][j]);
    __syncthreads();
  }
  #pragma unroll
  for (int i = 0; i < 4; ++i){
    const int r0 = rowBase + wr*64 + i*16 + l4*4;
    #pragma unroll
    for (int j = 0; j < 4; ++j){
      const int c = colBase + wc*64 + j*16 + l15;
      const float bb = bias ? bias[c] : 0.f;
      #pragma unroll
      for (int jr = 0; jr < 4; ++jr){
        const float v = acc[i][j][jr] + bb;
        const long rr = r0 + jr;
        if (!transposed){
          out[rr * 512 + c] = f2bf(v);
        } else {
          const long m = rr >> 7, s = rr & 127;
          out[(m * 512 + c) * 128 + s] = f2bf(v);
        }
      }
    }
  }
}

// ---- K,V projection, gemm97 structure: C[65536][1024] = mln * [Wk;Wv]^T --
__global__ __launch_bounds__(256) void gemm_kv97(const unsigned short* __restrict__ A,
                                                 const unsigned short* __restrict__ B,
                                                 const float* __restrict__ bk,
                                                 const float* __restrict__ bv,
                                                 unsigned short* __restrict__ kout,
                                                 unsigned short* __restrict__ vout){
  __shared__ unsigned short A_lds[4096];
  __shared__ unsigned short B_lds[4096];
  const int t = threadIdx.x, lane = t & 63, wid = t >> 6;
  const int l15 = lane & 15, l4 = lane >> 4;
  const int wr = wid >> 1, wc = wid & 1;
  const int b = blockIdx.x;               // 4096 blocks
  const int kk = b >> 3;
  const int colBase = (kk & 7) * 128;
  const long panel = (b & 7) + 8 * (kk >> 3);   // 0..511 (music index m)
  const long rowBase = panel * 128;
  f32x4 zero = {0.f,0.f,0.f,0.f};
  f32x4 acc[4][4];
  #pragma unroll
  for (int i = 0; i < 4; ++i)
    #pragma unroll
    for (int j = 0; j < 4; ++j) acc[i][j] = zero;
  for (int ks = 0; ks < 16; ++ks){
    const int k0 = ks * 32;
    #pragma unroll
    for (int h = 0; h < 2; ++h){
      const int p = h*256 + t;
      const int row = p >> 2, g = (p & 3) ^ ((row >> 1) & 3);
      gload16(A + (rowBase + row)*512 + k0 + g*8, A_lds + p*8);
      gload16(B + (long)(colBase + row)*512 + k0 + g*8, B_lds + p*8);
    }
    __syncthreads();
    short8 af[4], bfv[4];
    #pragma unroll
    for (int i = 0; i < 4; ++i){
      const int ra = wr*64 + i*16 + l15;
      af[i]  = *(const short8*)(A_lds + (ra*4 + (l4 ^ ((ra >> 1) & 3)))*8);
      const int rb = wc*64 + i*16 + l15;
      bfv[i] = *(const short8*)(B_lds + (rb*4 + (l4 ^ ((rb >> 1) & 3)))*8);
    }
    #pragma unroll
    for (int i = 0; i < 4; ++i)
      #pragma unroll
      for (int j = 0; j < 4; ++j)
        acc[i][j] = mfma16(af[i], bfv[j], acc[i][j]);
    __syncthreads();
  }
  if (colBase < 512){
    #pragma unroll
    for (int i = 0; i < 4; ++i){
      const long r0 = rowBase + wr*64 + i*16 + l4*4;
      #pragma unroll
      for (int j = 0; j < 4; ++j){
        const int c = colBase + wc*64 + j*16 + l15;
        const float bb = bk[c];
        #pragma unroll
        for (int jr = 0; jr < 4; ++jr)
          kout[(r0 + jr)*512 + c] = f2bf(acc[i][j][jr] + bb);
      }
    }
  } else {
    #pragma unroll
    for (int i = 0; i < 4; ++i){
      const int s0 = wr*64 + i*16 + l4*4;
      #pragma unroll
      for (int j = 0; j < 4; ++j){
        const int d = colBase - 512 + wc*64 + j*16 + l15;
        const float bb = bv[d];
        #pragma unroll
        for (int jr = 0; jr < 4; ++jr)
          vout[(panel*512 + d)*128 + s0 + jr] = f2bf(acc[i][j][jr] + bb);
      }
    }
  }
}

// ---------------- attention: per (m, 32-row q block), XCD-swizzled --------
// K and V tiles staged via global_load_lds (linear LDS + granule-XOR swizzle,
// same recipe as gemm97). Q staged once via vector loads (padded, one-time).
__global__ __launch_bounds__(256) void attn_kernel(const unsigned short* __restrict__ q,
                                                   const unsigned short* __restrict__ k,
                                                   const unsigned short* __restrict__ vT,
                                                   const int* __restrict__ mask,
                                                   unsigned short* __restrict__ attn){
  __shared__ __align__(16) char smem[58880];
  unsigned short (*q_lds)[520] = (unsigned short (*)[520])smem;        // [0,33280)
  unsigned short* k_lin = (unsigned short*)(smem + 33280);             // 8192 B (QK phase)
  float (*lg)[132]      = (float (*)[132])(smem + 33280);              // 16896 B (post-QK)
  unsigned short (*w_lds)[136] = (unsigned short (*)[136])(smem + 50176); // 8704 B
  unsigned short* v_lin = (unsigned short*)smem;                       // 32768 B (post-softmax)
  const int bq = blockIdx.x;
  const int m = (bq & 7) + 8 * ((bq >> 3) >> 3);   // same-XCD blocks share m
  const int nb = (bq >> 3) & 7;
  const int t = threadIdx.x, lane = t & 63, wid = t >> 6;
  const int l15 = lane & 15, l4 = lane >> 4;
  {
    const int r = t >> 3, c0 = (t & 7) * 64;
    const unsigned short* src = q + (long)(nb*32 + r) * 512 + c0;
    #pragma unroll
    for (int i = 0; i < 64; i += 8)
      *(short8*)&q_lds[r][c0 + i] = *(const short8*)(src + i);
  }
  f32x4 zero = {0.f,0.f,0.f,0.f};
  f32x4 acc[2][2];
  acc[0][0]=zero; acc[0][1]=zero; acc[1][0]=zero; acc[1][1]=zero;
  const unsigned short* kbase = k + (long)m * 128 * 512;
  for (int ks = 0; ks < 16; ++ks){
    const int k0 = ks * 32;
    #pragma unroll
    for (int h = 0; h < 2; ++h){
      const int p = h*256 + t;
      const int row = p >> 2, g = (p & 3) ^ ((row >> 1) & 3);
      gload16(kbase + (long)row*512 + k0 + g*8, k_lin + p*8);
    }
    __syncthreads();
    short8 af[2], bfv[2];
    #pragma unroll
    for (int i = 0; i < 2; ++i) af[i] = *(const short8*)&q_lds[i*16 + l15][k0 + l4*8];
    #pragma unroll
    for (int i = 0; i < 2; ++i){
      const int rb = wid*32 + i*16 + l15;
      bfv[i] = *(const short8*)(k_lin + (rb*4 + (l4 ^ ((rb >> 1) & 3)))*8);
    }
    #pragma unroll
    for (int i = 0; i < 2; ++i)
      #pragma unroll
      for (int j = 0; j < 2; ++j)
        acc[i][j] = mfma16(af[i], bfv[j], acc[i][j]);
    __syncthreads();
  }
  const float scale = 0.04419417382415922f; // 1/sqrt(512)
  #pragma unroll
  for (int i = 0; i < 2; ++i)
    #pragma unroll
    for (int j = 0; j < 2; ++j)
      #pragma unroll
      for (int jr = 0; jr < 4; ++jr)
        lg[i*16 + l4*4 + jr][wid*32 + j*16 + l15] = acc[i][j][jr] * scale;
  __syncthreads();
  {
    const int row = t >> 3, u = t & 7;
    const int* mrow = mask + m * 128;
    float vals[16];
    float mx = -3.0e38f;
    #pragma unroll
    for (int i = 0; i < 16; ++i){
      const int s = u*16 + i;
      const float vv = (mrow[s] == 0) ? -3.0e38f : lg[row][s];
      vals[i] = vv;
      mx = fmaxf(mx, vv);
    }
    mx = fmaxf(mx, __shfl_xor(mx, 1));
    mx = fmaxf(mx, __shfl_xor(mx, 2));
    mx = fmaxf(mx, __shfl_xor(mx, 4));
    float sum = 0.f;
    #pragma unroll
    for (int i = 0; i < 16; ++i){
      const float e = __expf(vals[i] - mx);
      vals[i] = e;
      sum += e;
    }
    sum += __shfl_xor(sum, 1);
    sum += __shfl_xor(sum, 2);
    sum += __shfl_xor(sum, 4);
    const float inv = (sum > 0.f) ? (1.f / sum) : 0.f;
    #pragma unroll
    for (int i = 0; i < 16; i += 4){
      u16x4 o = { f2bf(vals[i]*inv), f2bf(vals[i+1]*inv),
                  f2bf(vals[i+2]*inv), f2bf(vals[i+3]*inv) };
      *(u16x4*)&w_lds[row][u*16 + i] = o;
    }
  }
  const long rowb = (long)m * 256 + nb * 32;
  const unsigned short* vbase = vT + (long)m * 512 * 128;
  for (int db = 0; db < 4; ++db){
    __syncthreads();                  // w_lds visible / v_lin free
    #pragma unroll
    for (int it = 0; it < 8; ++it){
      const int p = it*256 + t;
      const int row = p >> 4, g = (p & 15) ^ (row & 7);
      gload16(vbase + (long)(db*128 + row)*128 + g*8, v_lin + p*8);
    }
    __syncthreads();
    f32x4 pacc[2][2];
    pacc[0][0]=zero; pacc[0][1]=zero; pacc[1][0]=zero; pacc[1][1]=zero;
    #pragma unroll
    for (int ks2 = 0; ks2 < 4; ++ks2){
      short8 wf[2], vf[2];
      #pragma unroll
      for (int i = 0; i < 2; ++i) wf[i] = *(const short8*)&w_lds[i*16 + l15][ks2*32 + l4*8];
      #pragma unroll
      for (int i = 0; i < 2; ++i){
        const int rv = wid*32 + i*16 + l15;
        vf[i] = *(const short8*)(v_lin + (rv*16 + ((ks2*4 + l4) ^ (rv & 7)))*8);
      }
      #pragma unroll
      for (int i = 0; i < 2; ++i)
        #pragma unroll
        for (int j = 0; j < 2; ++j)
          pacc[i][j] = mfma16(wf[i], vf[j], pacc[i][j]);
    }
    #pragma unroll
    for (int i = 0; i < 2; ++i)
      #pragma unroll
      for (int j = 0; j < 2; ++j)
        #pragma unroll
        for (int jr = 0; jr < 4; ++jr)
          attn[(rowb + i*16 + l4*4 + jr) * 512 + db*128 + wid*32 + j*16 + l15] =
              f2bf(pacc[i][j][jr]);
  }
}

// ---- m97-replica GEMM chunk: C[16384][1024] = A_chunk[16384][512]*Bcat^T --
// 1024 blocks; XCD-panel swizzle over the chunk's 128 row-panels.
__global__ __launch_bounds__(256) void gemm97(const unsigned short* __restrict__ A,
                                              const unsigned short* __restrict__ B,
                                              unsigned short* __restrict__ C){
  __shared__ unsigned short A_lds[4096];
  __shared__ unsigned short B_lds[4096];
  const int t = threadIdx.x, lane = t & 63, wid = t >> 6;
  const int l15 = lane & 15, l4 = lane >> 4;
  const int wr = wid >> 1, wc = wid & 1;
  const int b = blockIdx.x;
  const int kk = b >> 3;
  const int colBase = (kk & 7) * 128;
  const long rowBase = ((long)(b & 7) + 8 * (kk >> 3)) * 128;
  f32x4 zero = {0.f,0.f,0.f,0.f};
  f32x4 acc[4][4];
  #pragma unroll
  for (int i = 0; i < 4; ++i)
    #pragma unroll
    for (int j = 0; j < 4; ++j) acc[i][j] = zero;
  for (int ks = 0; ks < 16; ++ks){
    const int k0 = ks * 32;
    #pragma unroll
    for (int h = 0; h < 2; ++h){
      const int p = h*256 + t;
      const int row = p >> 2, g = (p & 3) ^ ((row >> 1) & 3);
      gload16(A + (rowBase + row)*512 + k0 + g*8, A_lds + p*8);
      gload16(B + (long)(colBase + row)*512 + k0 + g*8, B_lds + p*8);
    }
    __syncthreads();
    short8 af[4], bfv[4];
    #pragma unroll
    for (int i = 0; i < 4; ++i){
      const int ra = wr*64 + i*16 + l15;
      af[i]  = *(const short8*)(A_lds + (ra*4 + (l4 ^ ((ra >> 1) & 3)))*8);
      const int rb = wc*64 + i*16 + l15;
      bfv[i] = *(const short8*)(B_lds + (rb*4 + (l4 ^ ((rb >> 1) & 3)))*8);
    }
    #pragma unroll
    for (int i = 0; i < 4; ++i)
      #pragma unroll
      for (int j = 0; j < 4; ++j)
        acc[i][j] = mfma16(af[i], bfv[j], acc[i][j]);
    __syncthreads();
  }
  #pragma unroll
  for (int i = 0; i < 4; ++i){
    const long r0 = rowBase + wr*64 + i*16 + l4*4;
    #pragma unroll
    for (int j = 0; j < 4; ++j){
      const int c = colBase + wc*64 + j*16 + l15;
      #pragma unroll
      for (int jr = 0; jr < 4; ++jr)
        C[(r0 + jr)*1024 + c] = f2bf(acc[i][j][jr]);
    }
  }
}

// ---- LN epilogue, one wave per row, IN-PLACE in d_out --------------------
__global__ __launch_bounds__(256) void ln_epilogue(
    const unsigned short* Cb, float* out,   // SAME buffer; no __restrict__
    const float* __restrict__ bias_cat, const float* __restrict__ u,
    const float* __restrict__ v,
    const float* __restrict__ g2, const float* __restrict__ b2,
    const float* __restrict__ g3, const float* __restrict__ b3){
  const int wid = threadIdx.x >> 6, lane = threadIdx.x & 63;
  const long row = (long)blockIdx.x * 4 + wid;
  const unsigned short* cr = Cb + row * 1024;
  short8 ov = *(const short8*)(cr + lane * 8);
  short8 pv = *(const short8*)(cr + 512 + lane * 8);
  const int n0 = lane * 8;
  float4 bo0 = *(const float4*)(bias_cat + n0);
  float4 bo1 = *(const float4*)(bias_cat + n0 + 4);
  float4 c20 = *(const float4*)(bias_cat + 512 + n0);
  float4 c21 = *(const float4*)(bias_cat + 512 + n0 + 4);
  float o[8], p[8];
  #pragma unroll
  for (int j = 0; j < 4; ++j){
    o[j]   = bf2f((unsigned short)ov[j])   + ((const float*)&bo0)[j];
    o[4+j] = bf2f((unsigned short)ov[4+j]) + ((const float*)&bo1)[j];
    p[j]   = bf2f((unsigned short)pv[j])   + ((const float*)&c20)[j];
    p[4+j] = bf2f((unsigned short)pv[4+j]) + ((const float*)&c21)[j];
  }
  float s = 0.f, s2 = 0.f;
  #pragma unroll
  for (int j = 0; j < 8; ++j){ s += o[j]; s2 += o[j]*o[j]; }
  #pragma unroll
  for (int m = 1; m < 64; m <<= 1){ s += __shfl_xor(s, m); s2 += __shfl_xor(s2, m); }
  const float mu2 = s * (1.f/512.f);
  const float rstd2 = rsqrtf(s2 * (1.f/512.f) - mu2*mu2 + 1e-5f);
  float4 uv0 = *(const float4*)(u + n0), uv1 = *(const float4*)(u + n0 + 4);
  float4 vv0 = *(const float4*)(v + n0), vv1 = *(const float4*)(v + n0 + 4);
  float4 g20v = *(const float4*)(g2 + n0), g21v = *(const float4*)(g2 + n0 + 4);
  float4 b20v = *(const float4*)(b2 + n0), b21v = *(const float4*)(b2 + n0 + 4);
  float y[8];
  #pragma unroll
  for (int j = 0; j < 4; ++j){
    const float lin0 = rstd2 * (p[j]   - mu2 * ((const float*)&uv0)[j]) + ((const float*)&vv0)[j];
    const float lin1 = rstd2 * (p[4+j] - mu2 * ((const float*)&uv1)[j]) + ((const float*)&vv1)[j];
    const float oln0 = (o[j]   - mu2) * rstd2 * ((const float*)&g20v)[j] + ((const float*)&b20v)[j];
    const float oln1 = (o[4+j] - mu2) * rstd2 * ((const float*)&g21v)[j] + ((const float*)&b21v)[j];
    y[j]   = oln0 + lin0;
    y[4+j] = oln1 + lin1;
  }
  float t1 = 0.f, t2 = 0.f;
  #pragma unroll
  for (int j = 0; j < 8; ++j){ t1 += y[j]; t2 += y[j]*y[j]; }
  #pragma unroll
  for (int m = 1; m < 64; m <<= 1){ t1 += __shfl_xor(t1, m); t2 += __shfl_xor(t2, m); }
  const float mu3 = t1 * (1.f/512.f);
  const float rstd3 = rsqrtf(t2 * (1.f/512.f) - mu3*mu3 + 1e-5f);
  float4 g30v = *(const float4*)(g3 + n0), g31v = *(const float4*)(g3 + n0 + 4);
  float4 b30v = *(const float4*)(b3 + n0), b31v = *(const float4*)(b3 + n0 + 4);
  float4 r0, r1;
  #pragma unroll
  for (int j = 0; j < 4; ++j){
    ((float*)&r0)[j] = (y[j]   - mu3) * rstd3 * ((const float*)&g30v)[j] + ((const float*)&b30v)[j];
    ((float*)&r1)[j] = (y[4+j] - mu3) * rstd3 * ((const float*)&g31v)[j] + ((const float*)&b31v)[j];
  }
  *(float4*)(out + row * 512 + n0)     = r0;
  *(float4*)(out + row * 512 + n0 + 4) = r1;
}

extern "C" void kernel_launch(void* const* d_in, const int* in_sizes, int n_in,
                              void* d_out, int out_size, void* d_ws, size_t ws_size,
                              hipStream_t stream){
  const float* video = (const float*)d_in[0];
  const float* music = (const float*)d_in[1];
  const int*   mask  = (const int*)d_in[2];
  const float* ln1g  = (const float*)d_in[3];
  const float* ln1b  = (const float*)d_in[4];
  const float* Wq = (const float*)d_in[5];  const float* bq = (const float*)d_in[6];
  const float* Wk = (const float*)d_in[7];  const float* bk = (const float*)d_in[8];
  const float* Wv = (const float*)d_in[9];  const float* bv = (const float*)d_in[10];
  const float* Wo = (const float*)d_in[11]; const float* bo = (const float*)d_in[12];
  const float* Wl = (const float*)d_in[13]; const float* bl = (const float*)d_in[14];
  const float* g2 = (const float*)d_in[15]; const float* b2 = (const float*)d_in[16];
  const float* g3 = (const float*)d_in[17]; const float* b3 = (const float*)d_in[18];

  // d_out scratch: stage-1/2 intermediates, then C (bf16), then final out (in-place)
  char* ob = (char*)d_out;
  unsigned short* mln   = (unsigned short*)ob;                  // [65536][512] bf16
  unsigned short* kbuf  = (unsigned short*)(ob + 67108864);     // [65536][512] bf16
  unsigned short* vTbuf = (unsigned short*)(ob + 134217728);    // [512][512][128] bf16
  unsigned short* Cbuf  = (unsigned short*)ob;                  // [131072][1024] bf16
  float* outp = (float*)d_out;

  char* wsb = (char*)d_ws;
  unsigned short* attnb = (unsigned short*)wsb;                 // [131072][512] bf16
  unsigned short* Wq_bf = (unsigned short*)(wsb + 134217728);
  unsigned short* KVcat = Wq_bf + 262144;                       // [1024][512]: Wk ; Wv
  unsigned short* q_ws  = KVcat + 524288;                       // [256][512] bf16
  unsigned short* vln   = q_ws + 131072;                        // [256][512] bf16
  unsigned short* Bcat  = vln + 131072;                         // [1024][512] bf16
  unsigned short* wlp   = Bcat + 524288;                        // [512][512] bf16
  unsigned short* WoT   = wlp + 262144;                         // [512][512] bf16
  float* bias_cat = (float*)(WoT + 262144);                     // [1024]
  float* u_vec    = bias_cat + 1024;                            // [512]
  float* v_vec    = u_vec + 512;                                // [512]

  cvt_f32_bf16<<<256, 256, 0, stream>>>(Wq, Wq_bf);
  cvt_f32_bf16<<<256, 256, 0, stream>>>(Wk, KVcat);
  cvt_f32_bf16<<<256, 256, 0, stream>>>(Wv, KVcat + 262144);
  cvt_f32_bf16<<<256, 256, 0, stream>>>(Wo, Bcat);              // Bcat rows 0..511 = Wo
  ln_weight_prep<<<128, 256, 0, stream>>>(Wl, g2, b2, bl, bo, wlp, u_vec, v_vec, bias_cat);
  transpose_bf<<<dim3(8, 8), 256, 0, stream>>>(Wo, WoT);
  gemm_bt<<<dim3(4, 4), 256, 0, stream>>>(wlp, WoT, nullptr, Bcat + 262144, 0); // W2

  ln_rows<<<16384, 256, 0, stream>>>(music, ln1g, ln1b, mln, 65536);
  ln_rows<<<64,    256, 0, stream>>>(video, ln1g, ln1b, vln, 256);

  gemm_bt<<<dim3(4, 2), 256, 0, stream>>>(vln, Wq_bf, bq, q_ws, 0);
  gemm_kv97<<<4096, 256, 0, stream>>>(mln, KVcat, bk, bv, kbuf, vTbuf);

  attn_kernel<<<4096, 256, 0, stream>>>(q_ws, kbuf, vTbuf, mask, attnb);

  // Chunked producer-consumer: C chunk (64MB) stays L3-resident; ln_epilogue
  // overwrites C bytes in-place with out -> C never needs HBM round-trip.
  for (int c = 0; c < 4; ++c){
    const long rowoff = (long)c * 32768;
    gemm97<<<2048, 256, 0, stream>>>(attnb + rowoff*512, Bcat, Cbuf + rowoff*1024);
    ln_epilogue<<<8192, 256, 0, stream>>>(Cbuf + rowoff*1024, outp + rowoff*512,
                                          bias_cat, u_vec, v_vec, g2, b2, g3, b3);
  }
}

// Round 10
// 659.408 us; speedup vs baseline: 1.4116x; 1.0355x over previous
//
#include <hip/hip_runtime.h>

typedef __attribute__((ext_vector_type(8))) short short8;
typedef __attribute__((ext_vector_type(4))) float f32x4;
typedef __attribute__((ext_vector_type(4))) unsigned short u16x4;

__device__ __forceinline__ unsigned short f2bf(float f){
  unsigned int u = __builtin_bit_cast(unsigned int, f);
  u = (u + 0x7FFFu + ((u >> 16) & 1u)) >> 16;
  return (unsigned short)u;
}
__device__ __forceinline__ float bf2f(unsigned short h){
  unsigned int u = ((unsigned int)h) << 16;
  return __builtin_bit_cast(float, u);
}
__device__ __forceinline__ f32x4 mfma16(short8 a, short8 b, f32x4 c){
  return __builtin_amdgcn_mfma_f32_16x16x32_bf16(a, b, c, 0, 0, 0);
}
// async global->LDS, 16B/lane; lds base wave-uniform (HW: base + lane*16)
__device__ __forceinline__ void gload16(const void* g, void* l){
  __builtin_amdgcn_global_load_lds((const __attribute__((address_space(1))) void*)g,
                                   (__attribute__((address_space(3))) void*)l, 16, 0, 0);
}

// ---------------- f32 -> bf16 conversion (exactly 512*512 elems) ----------
__global__ __launch_bounds__(256) void cvt_f32_bf16(const float* __restrict__ src,
                                                    unsigned short* __restrict__ dst){
  int i = (blockIdx.x * 256 + threadIdx.x) * 4;
  float4 v = *(const float4*)(src + i);
  u16x4 o = { f2bf(v.x), f2bf(v.y), f2bf(v.z), f2bf(v.w) };
  *(u16x4*)(dst + i) = o;
}

// ---------------- LayerNorm over D=512, one wave per row, bf16 out --------
__global__ __launch_bounds__(256) void ln_rows(const float* __restrict__ x,
                                               const float* __restrict__ g,
                                               const float* __restrict__ b,
                                               unsigned short* __restrict__ y,
                                               int nrows){
  const int wid = threadIdx.x >> 6, lane = threadIdx.x & 63;
  const int row = blockIdx.x * 4 + wid;
  if (row >= nrows) return;
  const float* xr = x + (long)row * 512;
  float4 v0 = *(const float4*)(xr + lane * 4);
  float4 v1 = *(const float4*)(xr + 256 + lane * 4);
  float s  = v0.x + v0.y + v0.z + v0.w + v1.x + v1.y + v1.z + v1.w;
  float s2 = v0.x*v0.x + v0.y*v0.y + v0.z*v0.z + v0.w*v0.w
           + v1.x*v1.x + v1.y*v1.y + v1.z*v1.z + v1.w*v1.w;
  #pragma unroll
  for (int m = 1; m < 64; m <<= 1){ s += __shfl_xor(s, m); s2 += __shfl_xor(s2, m); }
  const float mu = s * (1.f/512.f);
  const float rstd = rsqrtf(s2 * (1.f/512.f) - mu*mu + 1e-5f);
  float4 g0 = *(const float4*)(g + lane*4), g1 = *(const float4*)(g + 256 + lane*4);
  float4 b0 = *(const float4*)(b + lane*4), b1 = *(const float4*)(b + 256 + lane*4);
  u16x4 o0 = { f2bf((v0.x-mu)*rstd*g0.x + b0.x), f2bf((v0.y-mu)*rstd*g0.y + b0.y),
               f2bf((v0.z-mu)*rstd*g0.z + b0.z), f2bf((v0.w-mu)*rstd*g0.w + b0.w) };
  u16x4 o1 = { f2bf((v1.x-mu)*rstd*g1.x + b1.x), f2bf((v1.y-mu)*rstd*g1.y + b1.y),
               f2bf((v1.z-mu)*rstd*g1.z + b1.z), f2bf((v1.w-mu)*rstd*g1.w + b1.w) };
  *(u16x4*)(y + (long)row * 512 + lane * 4) = o0;
  *(u16x4*)(y + (long)row * 512 + 256 + lane * 4) = o1;
}

// ---- prep: Wl'[n][c]=Wl[n][c]*g2[c] (bf16); u[n]=sum Wl'; v[n]=Wl.b2+bl;
//      bias_cat[n]=bo[n]; bias_cat[512+n]=c2[n]=sum Wl'[n][c]*bo[c] ---------
__global__ __launch_bounds__(256) void ln_weight_prep(
    const float* __restrict__ Wl, const float* __restrict__ g2,
    const float* __restrict__ b2, const float* __restrict__ bl,
    const float* __restrict__ bo,
    unsigned short* __restrict__ wlp, float* __restrict__ u,
    float* __restrict__ v, float* __restrict__ bias_cat){
  const int wid = threadIdx.x >> 6, lane = threadIdx.x & 63;
  const int n = blockIdx.x * 4 + wid;
  const float* row = Wl + (long)n * 512;
  float su = 0.f, sv = 0.f, sc = 0.f;
  #pragma unroll
  for (int h = 0; h < 2; ++h){
    const int c0 = h * 256 + lane * 4;
    float4 w  = *(const float4*)(row + c0);
    float4 gg = *(const float4*)(g2 + c0);
    float4 bb = *(const float4*)(b2 + c0);
    float4 oo = *(const float4*)(bo + c0);
    float4 wp = { w.x*gg.x, w.y*gg.y, w.z*gg.z, w.w*gg.w };
    su += wp.x + wp.y + wp.z + wp.w;
    sv += w.x*bb.x + w.y*bb.y + w.z*bb.z + w.w*bb.w;
    sc += wp.x*oo.x + wp.y*oo.y + wp.z*oo.z + wp.w*oo.w;
    u16x4 o = { f2bf(wp.x), f2bf(wp.y), f2bf(wp.z), f2bf(wp.w) };
    *(u16x4*)(wlp + (long)n * 512 + c0) = o;
  }
  #pragma unroll
  for (int m = 1; m < 64; m <<= 1){
    su += __shfl_xor(su, m); sv += __shfl_xor(sv, m); sc += __shfl_xor(sc, m);
  }
  if (lane == 0){
    u[n] = su;
    v[n] = sv + bl[n];
    bias_cat[n] = bo[n];
    bias_cat[512 + n] = sc;
  }
}

// ---- transpose 512x512: dst[k][c] = bf16(src[c][k]) ----------------------
__global__ __launch_bounds__(256) void transpose_bf(const float* __restrict__ src,
                                                    unsigned short* __restrict__ dst){
  __shared__ float tile[64][65];
  const int t = threadIdx.x;
  const int k0 = blockIdx.x * 64, c0 = blockIdx.y * 64;
  const int j = t & 63, i = t >> 6;
  #pragma unroll
  for (int rr = 0; rr < 16; ++rr)
    tile[i + rr*4][j] = src[(long)(c0 + i + rr*4) * 512 + k0 + j];
  __syncthreads();
  #pragma unroll
  for (int rr = 0; rr < 16; ++rr)
    dst[(long)(k0 + i + rr*4) * 512 + c0 + j] = f2bf(tile[j][i + rr*4]);
}

// ---------------- C = A(rows x 512) * B(512 x 512)^T + bias ---------------
__global__ __launch_bounds__(256) void gemm_bt(const unsigned short* __restrict__ A,
                                               const unsigned short* __restrict__ B,
                                               const float* __restrict__ bias,
                                               unsigned short* __restrict__ out,
                                               int transposed){
  __shared__ unsigned short At[128][40];
  __shared__ unsigned short Bt[128][40];
  const int t = threadIdx.x, lane = t & 63, wid = t >> 6;
  const int l15 = lane & 15, l4 = lane >> 4;
  const int wr = wid >> 1, wc = wid & 1;
  const int rowBase = blockIdx.y * 128;
  const int colBase = blockIdx.x * 128;
  f32x4 zero = {0.f, 0.f, 0.f, 0.f};
  f32x4 acc[4][4];
  #pragma unroll
  for (int i = 0; i < 4; ++i)
    #pragma unroll
    for (int j = 0; j < 4; ++j) acc[i][j] = zero;
  const int sr = t >> 1, sh = (t & 1) * 16;
  for (int ks = 0; ks < 16; ++ks){
    const int k0 = ks * 32;
    const unsigned short* sa = A + (long)(rowBase + sr) * 512 + k0 + sh;
    *(short8*)&At[sr][sh]     = *(const short8*)sa;
    *(short8*)&At[sr][sh + 8] = *(const short8*)(sa + 8);
    const unsigned short* sb = B + (long)(colBase + sr) * 512 + k0 + sh;
    *(short8*)&Bt[sr][sh]     = *(const short8*)sb;
    *(short8*)&Bt[sr][sh + 8] = *(const short8*)(sb + 8);
    __syncthreads();
    short8 af[4], bfv[4];
    #pragma unroll
    for (int i = 0; i < 4; ++i) af[i]  = *(const short8*)&At[wr*64 + i*16 + l15][l4*8];
    #pragma unroll
    for (int i = 0; i < 4; ++i) bfv[i] = *(const short8*)&Bt[wc*64 + i*16 + l15][l4*8];
    #pragma unroll
    for (int i = 0; i < 4; ++i)
      #pragma unroll
      for (int j = 0; j < 4; ++j)
        acc[i][j] = mfma16(af[i], bfv[j], acc[i][j]);
    __syncthreads();
  }
  #pragma unroll
  for (int i = 0; i < 4; ++i){
    const int r0 = rowBase + wr*64 + i*16 + l4*4;
    #pragma unroll
    for (int j = 0; j < 4; ++j){
      const int c = colBase + wc*64 + j*16 + l15;
      const float bb = bias ? bias[c] : 0.f;
      #pragma unroll
      for (int jr = 0; jr < 4; ++jr){
        const float v = acc[i][j][jr] + bb;
        const long rr = r0 + jr;
        if (!transposed){
          out[rr * 512 + c] = f2bf(v);
        } else {
          const long m = rr >> 7, s = rr & 127;
          out[(m * 512 + c) * 128 + s] = f2bf(v);
        }
      }
    }
  }
}

// ---- K,V projection, gemm97 structure: C[65536][1024] = mln * [Wk;Wv]^T --
__global__ __launch_bounds__(256) void gemm_kv97(const unsigned short* __restrict__ A,
                                                 const unsigned short* __restrict__ B,
                                                 const float* __restrict__ bk,
                                                 const float* __restrict__ bv,
                                                 unsigned short* __restrict__ kout,
                                                 unsigned short* __restrict__ vout){
  __shared__ unsigned short A_lds[4096];
  __shared__ unsigned short B_lds[4096];
  const int t = threadIdx.x, lane = t & 63, wid = t >> 6;
  const int l15 = lane & 15, l4 = lane >> 4;
  const int wr = wid >> 1, wc = wid & 1;
  const int b = blockIdx.x;               // 4096 blocks
  const int kk = b >> 3;
  const int colBase = (kk & 7) * 128;
  const long panel = (b & 7) + 8 * (kk >> 3);   // 0..511 (music index m)
  const long rowBase = panel * 128;
  f32x4 zero = {0.f,0.f,0.f,0.f};
  f32x4 acc[4][4];
  #pragma unroll
  for (int i = 0; i < 4; ++i)
    #pragma unroll
    for (int j = 0; j < 4; ++j) acc[i][j] = zero;
  for (int ks = 0; ks < 16; ++ks){
    const int k0 = ks * 32;
    #pragma unroll
    for (int h = 0; h < 2; ++h){
      const int p = h*256 + t;
      const int row = p >> 2, g = (p & 3) ^ ((row >> 1) & 3);
      gload16(A + (rowBase + row)*512 + k0 + g*8, A_lds + p*8);
      gload16(B + (long)(colBase + row)*512 + k0 + g*8, B_lds + p*8);
    }
    __syncthreads();
    short8 af[4], bfv[4];
    #pragma unroll
    for (int i = 0; i < 4; ++i){
      const int ra = wr*64 + i*16 + l15;
      af[i]  = *(const short8*)(A_lds + (ra*4 + (l4 ^ ((ra >> 1) & 3)))*8);
      const int rb = wc*64 + i*16 + l15;
      bfv[i] = *(const short8*)(B_lds + (rb*4 + (l4 ^ ((rb >> 1) & 3)))*8);
    }
    #pragma unroll
    for (int i = 0; i < 4; ++i)
      #pragma unroll
      for (int j = 0; j < 4; ++j)
        acc[i][j] = mfma16(af[i], bfv[j], acc[i][j]);
    __syncthreads();
  }
  if (colBase < 512){
    #pragma unroll
    for (int i = 0; i < 4; ++i){
      const long r0 = rowBase + wr*64 + i*16 + l4*4;
      #pragma unroll
      for (int j = 0; j < 4; ++j){
        const int c = colBase + wc*64 + j*16 + l15;
        const float bb = bk[c];
        #pragma unroll
        for (int jr = 0; jr < 4; ++jr)
          kout[(r0 + jr)*512 + c] = f2bf(acc[i][j][jr] + bb);
      }
    }
  } else {
    #pragma unroll
    for (int i = 0; i < 4; ++i){
      const int s0 = wr*64 + i*16 + l4*4;
      #pragma unroll
      for (int j = 0; j < 4; ++j){
        const int d = colBase - 512 + wc*64 + j*16 + l15;
        const float bb = bv[d];
        #pragma unroll
        for (int jr = 0; jr < 4; ++jr)
          vout[(panel*512 + d)*128 + s0 + jr] = f2bf(acc[i][j][jr] + bb);
      }
    }
  }
}

// ---------------- attention: per (m, 64-row q block), XCD-swizzled --------
// 64 q-rows/block (2x MFMA per barrier), in-register wave-parallel softmax
// (no lg round-trip), gload_lds staging for K and V (verified recipes).
__global__ __launch_bounds__(256) void attn_kernel(const unsigned short* __restrict__ q,
                                                   const unsigned short* __restrict__ k,
                                                   const unsigned short* __restrict__ vT,
                                                   const int* __restrict__ mask,
                                                   unsigned short* __restrict__ attn){
  __shared__ __align__(16) char smem[74752];
  unsigned short (*q_lds)[520] = (unsigned short (*)[520])smem;        // [0,66560)
  unsigned short* k_lin = (unsigned short*)(smem + 66560);             // 8192 B
  // post-QK overlays (q region dead):
  unsigned short (*w_lds)[136] = (unsigned short (*)[136])smem;        // [0,17408)
  float* red = (float*)(smem + 17408);                                 // [64][8] f32
  unsigned short* v_lin = (unsigned short*)(smem + 19456);             // 32768 B
  const int b = blockIdx.x;               // 2048 blocks
  const int m = (b & 7) + 8 * ((b >> 3) >> 2);  // same-XCD blocks share m
  const int qb = (b >> 3) & 3;
  const int t = threadIdx.x, lane = t & 63, wid = t >> 6;
  const int l15 = lane & 15, l4 = lane >> 4;
  {
    const int r = t >> 2, c0 = (t & 3) * 128;
    const unsigned short* src = q + (long)(qb*64 + r) * 512 + c0;
    #pragma unroll
    for (int i = 0; i < 128; i += 8)
      *(short8*)&q_lds[r][c0 + i] = *(const short8*)(src + i);
  }
  f32x4 zero = {0.f,0.f,0.f,0.f};
  f32x4 acc[4][2];
  #pragma unroll
  for (int i = 0; i < 4; ++i){ acc[i][0] = zero; acc[i][1] = zero; }
  const unsigned short* kbase = k + (long)m * 128 * 512;
  for (int ks = 0; ks < 16; ++ks){
    const int k0 = ks * 32;
    #pragma unroll
    for (int h = 0; h < 2; ++h){
      const int p = h*256 + t;
      const int row = p >> 2, g = (p & 3) ^ ((row >> 1) & 3);
      gload16(kbase + (long)row*512 + k0 + g*8, k_lin + p*8);
    }
    __syncthreads();
    short8 af[4], bfv[2];
    #pragma unroll
    for (int i = 0; i < 4; ++i) af[i] = *(const short8*)&q_lds[i*16 + l15][k0 + l4*8];
    #pragma unroll
    for (int j = 0; j < 2; ++j){
      const int rb = wid*32 + j*16 + l15;
      bfv[j] = *(const short8*)(k_lin + (rb*4 + (l4 ^ ((rb >> 1) & 3)))*8);
    }
    #pragma unroll
    for (int i = 0; i < 4; ++i)
      #pragma unroll
      for (int j = 0; j < 2; ++j)
        acc[i][j] = mfma16(af[i], bfv[j], acc[i][j]);
    __syncthreads();
  }
  // ---- in-register wave-parallel softmax ----
  const float scale = 0.04419417382415922f; // 1/sqrt(512)
  const int* mrow = mask + m * 128;
  const int mk0 = mrow[wid*32 + l15];
  const int mk1 = mrow[wid*32 + 16 + l15];
  float e[4][2][4], wmax[4][4], wsum[4][4];
  #pragma unroll
  for (int i = 0; i < 4; ++i)
    #pragma unroll
    for (int jr = 0; jr < 4; ++jr){
      float v0 = mk0 ? acc[i][0][jr]*scale : -3.0e38f;
      float v1 = mk1 ? acc[i][1][jr]*scale : -3.0e38f;
      float mx = fmaxf(v0, v1);
      mx = fmaxf(mx, __shfl_xor(mx, 1));
      mx = fmaxf(mx, __shfl_xor(mx, 2));
      mx = fmaxf(mx, __shfl_xor(mx, 4));
      mx = fmaxf(mx, __shfl_xor(mx, 8));
      const float e0 = __expf(v0 - mx), e1 = __expf(v1 - mx);
      float sm = e0 + e1;
      sm += __shfl_xor(sm, 1);
      sm += __shfl_xor(sm, 2);
      sm += __shfl_xor(sm, 4);
      sm += __shfl_xor(sm, 8);
      e[i][0][jr] = e0; e[i][1][jr] = e1;
      wmax[i][jr] = mx; wsum[i][jr] = sm;
    }
  if (l15 == 0){
    #pragma unroll
    for (int i = 0; i < 4; ++i)
      #pragma unroll
      for (int jr = 0; jr < 4; ++jr){
        const int r = i*16 + l4*4 + jr;
        red[r*8 + wid*2]     = wmax[i][jr];
        red[r*8 + wid*2 + 1] = wsum[i][jr];
      }
  }
  __syncthreads();
  float inv[4][4];
  #pragma unroll
  for (int i = 0; i < 4; ++i)
    #pragma unroll
    for (int jr = 0; jr < 4; ++jr){
      const int r = i*16 + l4*4 + jr;
      float4 a = *(const float4*)(red + r*8);
      float4 c = *(const float4*)(red + r*8 + 4);
      const float gm = fmaxf(fmaxf(a.x, a.z), fmaxf(c.x, c.z));
      const float gs = a.y*__expf(a.x - gm) + a.w*__expf(a.z - gm)
                     + c.y*__expf(c.x - gm) + c.w*__expf(c.z - gm);
      inv[i][jr] = (gs > 0.f) ? (1.f / gs) : 0.f;
      const float sc = __expf(wmax[i][jr] - gm);
      #pragma unroll
      for (int j = 0; j < 2; ++j)
        w_lds[r][wid*32 + j*16 + l15] = f2bf(e[i][j][jr] * sc);
    }
  // ---- PV: attn = (W . V) * inv, per 128-d block ----
  const long rowb = (long)m * 256 + qb * 64;
  const unsigned short* vbase = vT + (long)m * 512 * 128;
  for (int db = 0; db < 4; ++db){
    __syncthreads();                  // w_lds visible / v_lin free
    #pragma unroll
    for (int it = 0; it < 8; ++it){
      const int p = it*256 + t;
      const int row = p >> 4, g = (p & 15) ^ (row & 7);
      gload16(vbase + (long)(db*128 + row)*128 + g*8, v_lin + p*8);
    }
    __syncthreads();
    f32x4 pacc[4][2];
    #pragma unroll
    for (int i = 0; i < 4; ++i){ pacc[i][0] = zero; pacc[i][1] = zero; }
    #pragma unroll
    for (int ks2 = 0; ks2 < 4; ++ks2){
      short8 wf[4], vf[2];
      #pragma unroll
      for (int i = 0; i < 4; ++i) wf[i] = *(const short8*)&w_lds[i*16 + l15][ks2*32 + l4*8];
      #pragma unroll
      for (int j = 0; j < 2; ++j){
        const int rv = wid*32 + j*16 + l15;
        vf[j] = *(const short8*)(v_lin + (rv*16 + ((ks2*4 + l4) ^ (rv & 7)))*8);
      }
      #pragma unroll
      for (int i = 0; i < 4; ++i)
        #pragma unroll
        for (int j = 0; j < 2; ++j)
          pacc[i][j] = mfma16(wf[i], vf[j], pacc[i][j]);
    }
    #pragma unroll
    for (int i = 0; i < 4; ++i)
      #pragma unroll
      for (int j = 0; j < 2; ++j)
        #pragma unroll
        for (int jr = 0; jr < 4; ++jr)
          attn[(rowb + i*16 + l4*4 + jr) * 512 + db*128 + wid*32 + j*16 + l15] =
              f2bf(pacc[i][j][jr] * inv[i][jr]);
  }
}

// ---- m97-replica GEMM chunk: C[16384][1024] = A_chunk[16384][512]*Bcat^T --
__global__ __launch_bounds__(256) void gemm97(const unsigned short* __restrict__ A,
                                              const unsigned short* __restrict__ B,
                                              unsigned short* __restrict__ C){
  __shared__ unsigned short A_lds[4096];
  __shared__ unsigned short B_lds[4096];
  const int t = threadIdx.x, lane = t & 63, wid = t >> 6;
  const int l15 = lane & 15, l4 = lane >> 4;
  const int wr = wid >> 1, wc = wid & 1;
  const int b = blockIdx.x;
  const int kk = b >> 3;
  const int colBase = (kk & 7) * 128;
  const long rowBase = ((long)(b & 7) + 8 * (kk >> 3)) * 128;
  f32x4 zero = {0.f,0.f,0.f,0.f};
  f32x4 acc[4][4];
  #pragma unroll
  for (int i = 0; i < 4; ++i)
    #pragma unroll
    for (int j = 0; j < 4; ++j) acc[i][j] = zero;
  for (int ks = 0; ks < 16; ++ks){
    const int k0 = ks * 32;
    #pragma unroll
    for (int h = 0; h < 2; ++h){
      const int p = h*256 + t;
      const int row = p >> 2, g = (p & 3) ^ ((row >> 1) & 3);
      gload16(A + (rowBase + row)*512 + k0 + g*8, A_lds + p*8);
      gload16(B + (long)(colBase + row)*512 + k0 + g*8, B_lds + p*8);
    }
    __syncthreads();
    short8 af[4], bfv[4];
    #pragma unroll
    for (int i = 0; i < 4; ++i){
      const int ra = wr*64 + i*16 + l15;
      af[i]  = *(const short8*)(A_lds + (ra*4 + (l4 ^ ((ra >> 1) & 3)))*8);
      const int rb = wc*64 + i*16 + l15;
      bfv[i] = *(const short8*)(B_lds + (rb*4 + (l4 ^ ((rb >> 1) & 3)))*8);
    }
    #pragma unroll
    for (int i = 0; i < 4; ++i)
      #pragma unroll
      for (int j = 0; j < 4; ++j)
        acc[i][j] = mfma16(af[i], bfv[j], acc[i][j]);
    __syncthreads();
  }
  #pragma unroll
  for (int i = 0; i < 4; ++i){
    const long r0 = rowBase + wr*64 + i*16 + l4*4;
    #pragma unroll
    for (int j = 0; j < 4; ++j){
      const int c = colBase + wc*64 + j*16 + l15;
      #pragma unroll
      for (int jr = 0; jr < 4; ++jr)
        C[(r0 + jr)*1024 + c] = f2bf(acc[i][j][jr]);
    }
  }
}

// ---- LN epilogue, one wave per row, IN-PLACE in d_out --------------------
__global__ __launch_bounds__(256) void ln_epilogue(
    const unsigned short* Cb, float* out,   // SAME buffer; no __restrict__
    const float* __restrict__ bias_cat, const float* __restrict__ u,
    const float* __restrict__ v,
    const float* __restrict__ g2, const float* __restrict__ b2,
    const float* __restrict__ g3, const float* __restrict__ b3){
  const int wid = threadIdx.x >> 6, lane = threadIdx.x & 63;
  const long row = (long)blockIdx.x * 4 + wid;
  const unsigned short* cr = Cb + row * 1024;
  short8 ov = *(const short8*)(cr + lane * 8);
  short8 pv = *(const short8*)(cr + 512 + lane * 8);
  const int n0 = lane * 8;
  float4 bo0 = *(const float4*)(bias_cat + n0);
  float4 bo1 = *(const float4*)(bias_cat + n0 + 4);
  float4 c20 = *(const float4*)(bias_cat + 512 + n0);
  float4 c21 = *(const float4*)(bias_cat + 512 + n0 + 4);
  float o[8], p[8];
  #pragma unroll
  for (int j = 0; j < 4; ++j){
    o[j]   = bf2f((unsigned short)ov[j])   + ((const float*)&bo0)[j];
    o[4+j] = bf2f((unsigned short)ov[4+j]) + ((const float*)&bo1)[j];
    p[j]   = bf2f((unsigned short)pv[j])   + ((const float*)&c20)[j];
    p[4+j] = bf2f((unsigned short)pv[4+j]) + ((const float*)&c21)[j];
  }
  float s = 0.f, s2 = 0.f;
  #pragma unroll
  for (int j = 0; j < 8; ++j){ s += o[j]; s2 += o[j]*o[j]; }
  #pragma unroll
  for (int m = 1; m < 64; m <<= 1){ s += __shfl_xor(s, m); s2 += __shfl_xor(s2, m); }
  const float mu2 = s * (1.f/512.f);
  const float rstd2 = rsqrtf(s2 * (1.f/512.f) - mu2*mu2 + 1e-5f);
  float4 uv0 = *(const float4*)(u + n0), uv1 = *(const float4*)(u + n0 + 4);
  float4 vv0 = *(const float4*)(v + n0), vv1 = *(const float4*)(v + n0 + 4);
  float4 g20v = *(const float4*)(g2 + n0), g21v = *(const float4*)(g2 + n0 + 4);
  float4 b20v = *(const float4*)(b2 + n0), b21v = *(const float4*)(b2 + n0 + 4);
  float y[8];
  #pragma unroll
  for (int j = 0; j < 4; ++j){
    const float lin0 = rstd2 * (p[j]   - mu2 * ((const float*)&uv0)[j]) + ((const float*)&vv0)[j];
    const float lin1 = rstd2 * (p[4+j] - mu2 * ((const float*)&uv1)[j]) + ((const float*)&vv1)[j];
    const float oln0 = (o[j]   - mu2) * rstd2 * ((const float*)&g20v)[j] + ((const float*)&b20v)[j];
    const float oln1 = (o[4+j] - mu2) * rstd2 * ((const float*)&g21v)[j] + ((const float*)&b21v)[j];
    y[j]   = oln0 + lin0;
    y[4+j] = oln1 + lin1;
  }
  float t1 = 0.f, t2 = 0.f;
  #pragma unroll
  for (int j = 0; j < 8; ++j){ t1 += y[j]; t2 += y[j]*y[j]; }
  #pragma unroll
  for (int m = 1; m < 64; m <<= 1){ t1 += __shfl_xor(t1, m); t2 += __shfl_xor(t2, m); }
  const float mu3 = t1 * (1.f/512.f);
  const float rstd3 = rsqrtf(t2 * (1.f/512.f) - mu3*mu3 + 1e-5f);
  float4 g30v = *(const float4*)(g3 + n0), g31v = *(const float4*)(g3 + n0 + 4);
  float4 b30v = *(const float4*)(b3 + n0), b31v = *(const float4*)(b3 + n0 + 4);
  float4 r0, r1;
  #pragma unroll
  for (int j = 0; j < 4; ++j){
    ((float*)&r0)[j] = (y[j]   - mu3) * rstd3 * ((const float*)&g30v)[j] + ((const float*)&b30v)[j];
    ((float*)&r1)[j] = (y[4+j] - mu3) * rstd3 * ((const float*)&g31v)[j] + ((const float*)&b31v)[j];
  }
  *(float4*)(out + row * 512 + n0)     = r0;
  *(float4*)(out + row * 512 + n0 + 4) = r1;
}

extern "C" void kernel_launch(void* const* d_in, const int* in_sizes, int n_in,
                              void* d_out, int out_size, void* d_ws, size_t ws_size,
                              hipStream_t stream){
  const float* video = (const float*)d_in[0];
  const float* music = (const float*)d_in[1];
  const int*   mask  = (const int*)d_in[2];
  const float* ln1g  = (const float*)d_in[3];
  const float* ln1b  = (const float*)d_in[4];
  const float* Wq = (const float*)d_in[5];  const float* bq = (const float*)d_in[6];
  const float* Wk = (const float*)d_in[7];  const float* bk = (const float*)d_in[8];
  const float* Wv = (const float*)d_in[9];  const float* bv = (const float*)d_in[10];
  const float* Wo = (const float*)d_in[11]; const float* bo = (const float*)d_in[12];
  const float* Wl = (const float*)d_in[13]; const float* bl = (const float*)d_in[14];
  const float* g2 = (const float*)d_in[15]; const float* b2 = (const float*)d_in[16];
  const float* g3 = (const float*)d_in[17]; const float* b3 = (const float*)d_in[18];

  // d_out scratch: stage-1/2 intermediates, then C (bf16), then final out (in-place)
  char* ob = (char*)d_out;
  unsigned short* mln   = (unsigned short*)ob;                  // [65536][512] bf16
  unsigned short* kbuf  = (unsigned short*)(ob + 67108864);     // [65536][512] bf16
  unsigned short* vTbuf = (unsigned short*)(ob + 134217728);    // [512][512][128] bf16
  unsigned short* Cbuf  = (unsigned short*)ob;                  // [131072][1024] bf16
  float* outp = (float*)d_out;

  char* wsb = (char*)d_ws;
  unsigned short* attnb = (unsigned short*)wsb;                 // [131072][512] bf16
  unsigned short* Wq_bf = (unsigned short*)(wsb + 134217728);
  unsigned short* KVcat = Wq_bf + 262144;                       // [1024][512]: Wk ; Wv
  unsigned short* q_ws  = KVcat + 524288;                       // [256][512] bf16
  unsigned short* vln   = q_ws + 131072;                        // [256][512] bf16
  unsigned short* Bcat  = vln + 131072;                         // [1024][512] bf16
  unsigned short* wlp   = Bcat + 524288;                        // [512][512] bf16
  unsigned short* WoT   = wlp + 262144;                         // [512][512] bf16
  float* bias_cat = (float*)(WoT + 262144);                     // [1024]
  float* u_vec    = bias_cat + 1024;                            // [512]
  float* v_vec    = u_vec + 512;                                // [512]

  cvt_f32_bf16<<<256, 256, 0, stream>>>(Wq, Wq_bf);
  cvt_f32_bf16<<<256, 256, 0, stream>>>(Wk, KVcat);
  cvt_f32_bf16<<<256, 256, 0, stream>>>(Wv, KVcat + 262144);
  cvt_f32_bf16<<<256, 256, 0, stream>>>(Wo, Bcat);              // Bcat rows 0..511 = Wo
  ln_weight_prep<<<128, 256, 0, stream>>>(Wl, g2, b2, bl, bo, wlp, u_vec, v_vec, bias_cat);
  transpose_bf<<<dim3(8, 8), 256, 0, stream>>>(Wo, WoT);
  gemm_bt<<<dim3(4, 4), 256, 0, stream>>>(wlp, WoT, nullptr, Bcat + 262144, 0); // W2

  ln_rows<<<16384, 256, 0, stream>>>(music, ln1g, ln1b, mln, 65536);
  ln_rows<<<64,    256, 0, stream>>>(video, ln1g, ln1b, vln, 256);

  gemm_bt<<<dim3(4, 2), 256, 0, stream>>>(vln, Wq_bf, bq, q_ws, 0);
  gemm_kv97<<<4096, 256, 0, stream>>>(mln, KVcat, bk, bv, kbuf, vTbuf);

  attn_kernel<<<2048, 256, 0, stream>>>(q_ws, kbuf, vTbuf, mask, attnb);

  // Chunked producer-consumer: C chunk (64MB) stays L3-resident; ln_epilogue
  // overwrites C bytes in-place with out -> C never needs HBM round-trip.
  for (int c = 0; c < 4; ++c){
    const long rowoff = (long)c * 32768;
    gemm97<<<2048, 256, 0, stream>>>(attnb + rowoff*512, Bcat, Cbuf + rowoff*1024);
    ln_epilogue<<<8192, 256, 0, stream>>>(Cbuf + rowoff*1024, outp + rowoff*512,
                                          bias_cat, u_vec, v_vec, g2, b2, g3, b3);
  }
}